// Round 1
// 411.379 us; speedup vs baseline: 1.8343x; 1.8343x over previous
//
#include <hip/hip_runtime.h>

#define B_ 64
#define D_ 512
#define N_ 1200
#define K_ 64
#define NT2CNT 19   // ceil(1200/64) pixel tiles for logits kernels
#define NT3 16      // n-tile for k_vlad (divides 1200: 75 tiles)
#define PT 32       // fused-fallback pixels per tile
#define NTILES 38   // fused-fallback tiles

typedef __attribute__((ext_vector_type(8))) short bf16x8;
typedef __attribute__((ext_vector_type(4))) float f32x4;

__device__ __forceinline__ float bf2f(unsigned short u) {
  union { unsigned int i; float f; } v; v.i = ((unsigned int)u) << 16; return v.f;
}
__device__ __forceinline__ unsigned short f2bf(float f) {
  unsigned int u = __float_as_uint(f);
  u += 0x7FFFu + ((u >> 16) & 1u);   // round-to-nearest-even
  return (unsigned short)(u >> 16);
}

// ---------------- K0: split w into fragment-ordered bf16 hi/lo -------------
// grid 64 = (wv 0..3)*16 + dstep 0..15; 64 threads (1 wave).
// frag element j of lane l for (wv,dstep): w[16*wv + (l&15)][dstep*32 + 8*(l>>4) + j]
// stored contiguously so k_logits_mfma wave-loads are coalesced 16B/lane.
__global__ __launch_bounds__(64) void k_wsplit(
    const float* __restrict__ w,
    unsigned short* __restrict__ wfh, unsigned short* __restrict__ wfl)
{
  const int blk = blockIdx.x;
  const int wv = blk >> 4, dstep = blk & 15;
  const int l = threadIdx.x;
  const int row = wv * 16 + (l & 15);
  const int dbase = dstep * 32 + 8 * (l >> 4);
  const size_t o = ((size_t)blk * 64 + l) * 8;
#pragma unroll
  for (int j = 0; j < 8; ++j) {
    const float v = w[row * D_ + dbase + j];
    const unsigned int u = __float_as_uint(v);
    const unsigned int h = u & 0xFFFF0000u;      // truncation: hi is EXACT
    wfh[o + j] = (unsigned short)(h >> 16);
    wfl[o + j] = f2bf(v - __uint_as_float(h));   // residual, RNE to bf16
  }
}

// ---------------- K1 (MFMA): L2norm + logits(3-pass split bf16) + softmax --
// grid (19, 64), block 256 (4 waves). Wave wv owns k-rows 16wv..16wv+15,
// all 64 pixels of the tile (4 n-subtiles of 16). acc[s] = 16x16 C-frag.
// x staged per 128-d chunk as bf16 hi/lo in LDS, row stride 136 bf16
// (= 17 x 16B slots: odd slot stride -> conflict-free ds_read_b128).
__global__ __launch_bounds__(256) void k_logits_mfma(
    const float* __restrict__ x, const unsigned short* __restrict__ wfh,
    const unsigned short* __restrict__ wfl, unsigned short* __restrict__ a_bf,
    float* __restrict__ invn_ws, float* __restrict__ asum_part)
{
  const int nt = blockIdx.x, b = blockIdx.y;
  const int n0 = nt * 64;
  const int t = threadIdx.x;
  const int lane = t & 63, wv = t >> 6;

  __shared__ __align__(16) unsigned short xbuf[2][2][64][136];  // [dbuf][hi/lo][n][d+pad] 69.6 KB
  __shared__ float nsq_s[4][64];
  __shared__ float red_s[3][64];     // [0]=invn, [1]=max, [2]=1/sum
  float (*ls)[66] = reinterpret_cast<float(*)[66]>(&xbuf[0][0][0][0]);  // overlay (16.9 KB < 17.4 KB)

  // conversion identity: thread owns pixel n_l, d-stripe dg*32 per chunk
  const int n_l = t & 63, dg = t >> 6;
  const int nc = min(n0 + n_l, N_ - 1);            // clamp ragged tile
  const float* xb = x + (size_t)b * D_ * N_ + nc;
  float nsq = 0.f;

  f32x4 acc[4] = {{0.f,0.f,0.f,0.f},{0.f,0.f,0.f,0.f},{0.f,0.f,0.f,0.f},{0.f,0.f,0.f,0.f}};

  auto conv = [&](int c, int buf) {
    const int db = c * 128 + dg * 32;
#pragma unroll
    for (int i = 0; i < 32; i += 4) {
      const float f0 = xb[(size_t)(db + i + 0) * N_];   // coalesced over n
      const float f1 = xb[(size_t)(db + i + 1) * N_];
      const float f2 = xb[(size_t)(db + i + 2) * N_];
      const float f3 = xb[(size_t)(db + i + 3) * N_];
      nsq += f0 * f0 + f1 * f1 + f2 * f2 + f3 * f3;
      const unsigned int u0 = __float_as_uint(f0), u1 = __float_as_uint(f1);
      const unsigned int u2 = __float_as_uint(f2), u3 = __float_as_uint(f3);
      const unsigned int h0 = u0 & 0xFFFF0000u, h1 = u1 & 0xFFFF0000u;
      const unsigned int h2 = u2 & 0xFFFF0000u, h3 = u3 & 0xFFFF0000u;
      ushort4 hv, lv;
      hv.x = (unsigned short)(h0 >> 16); hv.y = (unsigned short)(h1 >> 16);
      hv.z = (unsigned short)(h2 >> 16); hv.w = (unsigned short)(h3 >> 16);
      lv.x = f2bf(f0 - __uint_as_float(h0)); lv.y = f2bf(f1 - __uint_as_float(h1));
      lv.z = f2bf(f2 - __uint_as_float(h2)); lv.w = f2bf(f3 - __uint_as_float(h3));
      *(ushort4*)&xbuf[buf][0][n_l][dg * 32 + i] = hv;   // 8B writes, ~2-way eff.
      *(ushort4*)&xbuf[buf][1][n_l][dg * 32 + i] = lv;
    }
  };

  auto mstep = [&](int c, int buf) {
#pragma unroll
    for (int ds = 0; ds < 4; ++ds) {
      const int fi = (wv * 16 + c * 4 + ds) * 64 + lane;
      const bf16x8 ah = ((const bf16x8*)wfh)[fi];   // coalesced 16B/lane (L2-hot)
      const bf16x8 al = ((const bf16x8*)wfl)[fi];
#pragma unroll
      for (int s = 0; s < 4; ++s) {
        const unsigned short* ph = &xbuf[buf][0][s * 16 + (lane & 15)][ds * 32 + 8 * (lane >> 4)];
        const unsigned short* pl = &xbuf[buf][1][s * 16 + (lane & 15)][ds * 32 + 8 * (lane >> 4)];
        const bf16x8 bh = *(const bf16x8*)ph;       // ds_read_b128, conflict-free
        const bf16x8 bl = *(const bf16x8*)pl;
        // 3-pass fp32-split: hi*hi + lo*hi + hi*lo (lo*lo dropped, <3e-5)
        acc[s] = __builtin_amdgcn_mfma_f32_16x16x32_bf16(ah, bh, acc[s], 0, 0, 0);
        acc[s] = __builtin_amdgcn_mfma_f32_16x16x32_bf16(al, bh, acc[s], 0, 0, 0);
        acc[s] = __builtin_amdgcn_mfma_f32_16x16x32_bf16(ah, bl, acc[s], 0, 0, 0);
      }
    }
  };

  conv(0, 0);
  __syncthreads();
  for (int c = 0; c < 4; ++c) {
    if (c < 3) conv(c + 1, (c + 1) & 1);   // prefetch next chunk into other buffer
    mstep(c, c & 1);
    __syncthreads();                        // guards both read-after-write and write-after-read
  }

  // ---- invn from fp32 partial sums (exact, same as previous kernel) ----
  nsq_s[dg][n_l] = nsq;
  __syncthreads();
  if (t < 64) {
    const float s4 = nsq_s[0][t] + nsq_s[1][t] + nsq_s[2][t] + nsq_s[3][t];
    const float inv = 1.f / fmaxf(sqrtf(s4), 1e-12f);
    red_s[0][t] = inv;
    if (n0 + t < N_) invn_ws[b * N_ + n0 + t] = inv;
  }
  __syncthreads();

  // ---- stash scaled logits to LDS (overlay; all MFMA reads are done) ----
  // C/D layout (verified): n = 16s + (lane&15), k = 16wv + 4*(lane>>4) + r
#pragma unroll
  for (int s = 0; s < 4; ++s) {
    const int n = 16 * s + (lane & 15);
    const float inv = red_s[0][n];
#pragma unroll
    for (int r = 0; r < 4; ++r) {
      const int k = 16 * wv + 4 * (lane >> 4) + r;
      ls[k][n] = acc[s][r] * inv;
    }
  }
  __syncthreads();

  // ---- per-pixel softmax stats (t<64; ~500 cyc, negligible) ----
  if (t < 64) {
    float m = -1e30f;
    for (int k = 0; k < K_; ++k) m = fmaxf(m, ls[k][t]);
    float ssum = 0.f;
    for (int k = 0; k < K_; ++k) ssum += __expf(ls[k][t] - m);
    red_s[1][t] = m;
    red_s[2][t] = 1.f / ssum;
  }
  __syncthreads();

  // ---- a = softmax, write a_bf (raw, invn NOT folded: k_vlad unchanged) ----
#pragma unroll
  for (int s = 0; s < 4; ++s) {
    const int n = 16 * s + (lane & 15);
    const bool valid = (n0 + n) < N_;
    const float inv = red_s[0][n], mv = red_s[1][n], si = red_s[2][n];
#pragma unroll
    for (int r = 0; r < 4; ++r) {
      const int k = 16 * wv + 4 * (lane >> 4) + r;
      const float av = valid ? __expf(acc[s][r] * inv - mv) * si : 0.f;
      ls[k][n] = av;
      if (valid) a_bf[((size_t)b * K_ + k) * N_ + n0 + n] = f2bf(av);
    }
  }
  __syncthreads();

  // ---- asum partials (same format as before) ----
  if (t < K_) {
    float su = 0.f;
#pragma unroll 8
    for (int p = 0; p < 64; ++p) su += ls[t][p];
    asum_part[(b * NT2CNT + nt) * K_ + t] = su;
  }
}

// ---------------- K1 (legacy VALU version, fallback if ws too small) ------
__global__ __launch_bounds__(256) void k_logits(
    const float* __restrict__ x, const float* __restrict__ w,
    unsigned short* __restrict__ a_bf, float* __restrict__ invn_ws,
    float* __restrict__ asum_part)
{
  const int nt = blockIdx.x, b = blockIdx.y;
  const int t = threadIdx.x;
  const int px = t & 63;
  const int kg = t >> 6;            // wave-uniform (w loads scalarize)
  const int n = nt * 64 + px;
  const bool valid = (n < N_);
  const int nc = valid ? n : (N_ - 1);
  __shared__ float lsh[K_][65];

  const float* xb = x + (size_t)b * D_ * N_ + nc;
  const float* wg = w + kg * 16 * D_;

  float acc[16];
#pragma unroll
  for (int j = 0; j < 16; ++j) acc[j] = 0.f;
  float nsq = 0.f;

  for (int d = 0; d < D_; d += 4) {
    const float xv0 = xb[(size_t)(d + 0) * N_];   // coalesced over px
    const float xv1 = xb[(size_t)(d + 1) * N_];
    const float xv2 = xb[(size_t)(d + 2) * N_];
    const float xv3 = xb[(size_t)(d + 3) * N_];
    nsq += xv0 * xv0 + xv1 * xv1 + xv2 * xv2 + xv3 * xv3;
#pragma unroll
    for (int j = 0; j < 16; ++j) {
      const float4 wv = *(const float4*)(wg + j * D_ + d);  // wave-uniform
      acc[j] = fmaf(xv0, wv.x, fmaf(xv1, wv.y, fmaf(xv2, wv.z, fmaf(xv3, wv.w, acc[j]))));
    }
  }
  const float invn = 1.f / fmaxf(sqrtf(nsq), 1e-12f);
  if (kg == 0 && valid) invn_ws[b * N_ + n] = invn;
#pragma unroll
  for (int j = 0; j < 16; ++j) lsh[kg * 16 + j][px] = acc[j] * invn;
  __syncthreads();
  float m = -1e30f;
  for (int k = 0; k < K_; ++k) m = fmaxf(m, lsh[k][px]);
  float s = 0.f;
  for (int k = 0; k < K_; ++k) s += __expf(lsh[k][px] - m);
  const float sinv = 1.f / s;
  float av[16];
#pragma unroll
  for (int j = 0; j < 16; ++j)
    av[j] = valid ? __expf(acc[j] * invn - m) * sinv : 0.f;
  __syncthreads();
#pragma unroll
  for (int j = 0; j < 16; ++j) lsh[kg * 16 + j][px] = av[j];
  if (valid) {
#pragma unroll
    for (int j = 0; j < 16; ++j)
      a_bf[((size_t)b * K_ + kg * 16 + j) * N_ + n] = f2bf(av[j]);
  }
  __syncthreads();
  if (t < K_) {
    float su = 0.f;
#pragma unroll 8
    for (int p = 0; p < 64; ++p) su += lsh[t][p];
    asum_part[(b * NT2CNT + nt) * K_ + t] = su;
  }
}

// ---------------- K2: vlad + intra-norm + global(=1/8) + fp32 out ---------
// grid 512: id = kg*64 + b. thread owns k=kg*8+j x d in {2t,2t+1}.
__global__ __launch_bounds__(256) void k_vlad(
    const float* __restrict__ x, const unsigned short* __restrict__ a_bf,
    const float* __restrict__ invn_ws, const float* __restrict__ asum_part,
    const float* __restrict__ cent, float* __restrict__ out)
{
  const int id = blockIdx.x;
  const int kg = id >> 6;
  const int b  = id & 63;
  const int t  = threadIdx.x;
  __shared__ float xs[NT3][518];
  __shared__ float as[8][NT3 + 2];
  __shared__ float asums[8];
  __shared__ float part[8][4];
  __shared__ float scale_s[8];

  if (t < 8) {
    float s = 0.f;
    for (int nt2 = 0; nt2 < NT2CNT; ++nt2)
      s += asum_part[(b * NT2CNT + nt2) * K_ + kg * 8 + t];
    asums[t] = s;
  }
  float acc[16];
#pragma unroll
  for (int i = 0; i < 16; ++i) acc[i] = 0.f;

  const float* xb = x + (size_t)b * D_ * N_;
  const int d0 = 2 * t;
  const int snl = t & 15, sdc = t >> 4;
  const int saj = t >> 4, sanl = t & 15;

  for (int n0 = 0; n0 < N_; n0 += NT3) {
    __syncthreads();
    {
      const float* xp = xb + (size_t)(sdc * 32) * N_ + (n0 + snl);
      float* xrow = &xs[snl][sdc * 32];
#pragma unroll
      for (int i = 0; i < 32; i += 2) {
        float2 w2;
        w2.x = xp[(size_t)i * N_];
        w2.y = xp[(size_t)(i + 1) * N_];
        *(float2*)(xrow + i) = w2;
      }
    }
    if (t < 128) {
      const float av = bf2f(a_bf[((size_t)b * K_ + kg * 8 + saj) * N_ + n0 + sanl])
                     * invn_ws[b * N_ + n0 + sanl];
      as[saj][sanl] = av;
    }
    __syncthreads();
#pragma unroll 2
    for (int nl = 0; nl < NT3; nl += 2) {
      const float2 x0 = *(const float2*)(&xs[nl][d0]);
      const float2 x1 = *(const float2*)(&xs[nl + 1][d0]);
#pragma unroll
      for (int j = 0; j < 8; ++j) {
        const float2 a2 = *(const float2*)(&as[j][nl]);
        acc[j * 2]     = fmaf(a2.x, x0.x, fmaf(a2.y, x1.x, acc[j * 2]));
        acc[j * 2 + 1] = fmaf(a2.x, x0.y, fmaf(a2.y, x1.y, acc[j * 2 + 1]));
      }
    }
  }
  __syncthreads();
  const int lane = t & 63, wv = t >> 6;
#pragma unroll
  for (int j = 0; j < 8; ++j) {
    const int k = kg * 8 + j;
    const float asv = asums[j];
    const float2 c2 = *(const float2*)(cent + (size_t)k * D_ + d0);
    acc[j * 2]     -= asv * c2.x;
    acc[j * 2 + 1] -= asv * c2.y;
    float v = acc[j * 2] * acc[j * 2] + acc[j * 2 + 1] * acc[j * 2 + 1];
#pragma unroll
    for (int o = 32; o > 0; o >>= 1) v += __shfl_down(v, o, 64);
    if (lane == 0) part[j][wv] = v;
  }
  __syncthreads();
  if (t < 8) {
    const float s = part[t][0] + part[t][1] + part[t][2] + part[t][3];
    scale_s[t] = 0.125f / fmaxf(sqrtf(s), 1e-12f);
  }
  __syncthreads();
#pragma unroll
  for (int j = 0; j < 8; ++j) {
    const int k = kg * 8 + j;
    const float f = scale_s[j];
    float2 o;
    o.x = acc[j * 2] * f;
    o.y = acc[j * 2 + 1] * f;
    *(float2*)(out + ((size_t)b * K_ + k) * D_ + d0) = o;
  }
}

// ---------------- Fallback: round-5 fused zero-workspace kernel -----------
__global__ __launch_bounds__(256) void k_fused(
    const float* __restrict__ x, const float* __restrict__ w,
    const float* __restrict__ cent, float* __restrict__ out)
{
  const int id = blockIdx.x;
  const int kq = id >> 6;
  const int b  = id & 63;
  const int t  = threadIdx.x;
  const int px = t & 31;
  const int kg = t >> 5;
  const bool own = (kg >> 1) == kq;
  const int khbase = (kg & 1) * 8;

  __shared__ unsigned short xs[PT][514];
  __shared__ float ls[K_][33];
  __shared__ float a_s[16][34];
  __shared__ float araw[16][34];
  __shared__ float asums[16];
  __shared__ float part[16][4];
  __shared__ float scale_s[16];

  if (t < 16) asums[t] = 0.f;
  float acc[32];
#pragma unroll
  for (int i = 0; i < 32; ++i) acc[i] = 0.f;
  const float* xb = x + (size_t)b * D_ * N_;

  for (int tile = 0; tile < NTILES; ++tile) {
    const int n0 = tile * PT;
    {
      const int row = t & 31, chunk = t >> 5;
      const int n = n0 + row;
      const int nc = (n < N_) ? n : (N_ - 1);
      const float* xp = xb + (size_t)(chunk * 64) * N_ + nc;
#pragma unroll
      for (int i = 0; i < 64; ++i)
        xs[row][chunk * 64 + i] = f2bf(xp[(size_t)i * N_]);
    }
    __syncthreads();
    float invn;
    {
      const ushort2* xr = (const ushort2*)xs[px];
      float lg[8] = {0,0,0,0,0,0,0,0};
      float nsq = 0.f;
      const float* wbase = w + (size_t)(kg * 8) * D_;
      for (int du = 0; du < D_ / 4; ++du) {
        const ushort2 p0 = xr[2 * du], p1 = xr[2 * du + 1];
        const float x0 = bf2f(p0.x), x1 = bf2f(p0.y), x2 = bf2f(p1.x), x3 = bf2f(p1.y);
        nsq += x0 * x0 + x1 * x1 + x2 * x2 + x3 * x3;
#pragma unroll
        for (int j = 0; j < 8; ++j) {
          const float4 wv = *(const float4*)(wbase + j * D_ + 4 * du);
          lg[j] = fmaf(x0,wv.x,fmaf(x1,wv.y,fmaf(x2,wv.z,fmaf(x3,wv.w,lg[j]))));
        }
      }
      invn = 1.f / fmaxf(sqrtf(nsq), 1e-12f);
#pragma unroll
      for (int j = 0; j < 8; ++j) ls[kg * 8 + j][px] = lg[j] * invn;
    }
    __syncthreads();
    {
      const bool valid = (n0 + px) < N_;
      float m = -1e30f;
      for (int k = 0; k < K_; ++k) m = fmaxf(m, ls[k][px]);
      float s = 0.f;
      for (int k = 0; k < K_; ++k) s += __expf(ls[k][px] - m);
      const float sinv = 1.f / s;
      if (own) {
#pragma unroll
        for (int j = 0; j < 8; ++j) {
          const float av = valid ? __expf(ls[kg * 8 + j][px] - m) * sinv : 0.f;
          araw[khbase + j][px] = av;
          a_s[khbase + j][px]  = av * invn;
        }
      }
    }
    __syncthreads();
    if (t < 16) {
      float su = 0.f;
#pragma unroll 8
      for (int p = 0; p < PT; ++p) su += araw[t][p];
      asums[t] += su;
    }
    {
#pragma unroll 2
      for (int nl = 0; nl < PT; nl += 2) {
        const ushort2 u0 = ((const ushort2*)xs[nl])[t];
        const ushort2 u1 = ((const ushort2*)xs[nl + 1])[t];
        const float x00 = bf2f(u0.x), x01 = bf2f(u0.y);
        const float x10 = bf2f(u1.x), x11 = bf2f(u1.y);
#pragma unroll
        for (int kh = 0; kh < 16; ++kh) {
          const float2 a2 = *(const float2*)(&a_s[kh][nl]);
          acc[kh * 2]     = fmaf(a2.x, x00, fmaf(a2.y, x10, acc[kh * 2]));
          acc[kh * 2 + 1] = fmaf(a2.x, x01, fmaf(a2.y, x11, acc[kh * 2 + 1]));
        }
      }
    }
    __syncthreads();
  }
  const int d0 = 2 * t;
  const int lane = t & 63, wv = t >> 6;
#pragma unroll
  for (int kh = 0; kh < 16; ++kh) {
    const int k = kq * 16 + kh;
    const float asv = asums[kh];
    const float2 c2 = *(const float2*)(cent + (size_t)k * D_ + d0);
    acc[kh * 2]     -= asv * c2.x;
    acc[kh * 2 + 1] -= asv * c2.y;
    float v = acc[kh * 2] * acc[kh * 2] + acc[kh * 2 + 1] * acc[kh * 2 + 1];
#pragma unroll
    for (int o = 32; o > 0; o >>= 1) v += __shfl_down(v, o, 64);
    if (lane == 0) part[kh][wv] = v;
  }
  __syncthreads();
  if (t < 16) {
    const float s = part[t][0] + part[t][1] + part[t][2] + part[t][3];
    scale_s[t] = 0.125f / fmaxf(sqrtf(s), 1e-12f);
  }
  __syncthreads();
#pragma unroll
  for (int kh = 0; kh < 16; ++kh) {
    const int k = kq * 16 + kh;
    const float f = scale_s[kh];
    float2 o;
    o.x = acc[kh * 2] * f;
    o.y = acc[kh * 2 + 1] * f;
    *(float2*)(out + ((size_t)b * K_ + k) * D_ + d0) = o;
  }
}

extern "C" void kernel_launch(void* const* d_in, const int* in_sizes, int n_in,
                              void* d_out, int out_size, void* d_ws, size_t ws_size,
                              hipStream_t stream)
{
  const float* x  = (const float*)d_in[0];   // (B,D,H,W) fp32
  const float* w  = (const float*)d_in[1];   // (K,D) fp32
  const float* ct = (const float*)d_in[2];   // (K,D) fp32
  float* out = (float*)d_out;                // (B, K*D) fp32

  const size_t wf_u16  = (size_t)K_ * D_;            // 32,768 per hi/lo array
  const size_t invn_f  = (size_t)B_ * N_;            // 76,800 floats
  const size_t asum_f  = (size_t)B_ * NT2CNT * K_;   // 77,824 floats
  const size_t a_u16   = (size_t)B_ * K_ * N_;       // 4,915,200 ushorts
  const size_t need_old  = (invn_f + asum_f) * 4 + a_u16 * 2;      // ~10.4 MB
  const size_t need_mfma = need_old + wf_u16 * 2 * 2;              // +131 KB

  if (ws_size >= need_mfma) {
    unsigned short* wfh = (unsigned short*)d_ws;
    unsigned short* wfl = wfh + wf_u16;
    float* invn_ws   = (float*)(wfl + wf_u16);
    float* asum_part = invn_ws + invn_f;
    unsigned short* a_bf = (unsigned short*)(asum_part + asum_f);
    hipLaunchKernelGGL(k_wsplit, dim3(64), dim3(64), 0, stream, w, wfh, wfl);
    hipLaunchKernelGGL(k_logits_mfma, dim3(NT2CNT, B_), dim3(256), 0, stream,
                       x, wfh, wfl, a_bf, invn_ws, asum_part);
    hipLaunchKernelGGL(k_vlad, dim3(512), dim3(256), 0, stream,
                       x, a_bf, invn_ws, asum_part, ct, out);
  } else if (ws_size >= need_old) {
    float* invn_ws   = (float*)d_ws;
    float* asum_part = invn_ws + invn_f;
    unsigned short* a_bf = (unsigned short*)(asum_part + asum_f);
    hipLaunchKernelGGL(k_logits, dim3(NT2CNT, B_), dim3(256), 0, stream,
                       x, w, a_bf, invn_ws, asum_part);
    hipLaunchKernelGGL(k_vlad, dim3(512), dim3(256), 0, stream,
                       x, a_bf, invn_ws, asum_part, ct, out);
  } else {
    hipLaunchKernelGGL(k_fused, dim3(256), dim3(256), 0, stream, x, w, ct, out);
  }
}

// Round 2
// 312.626 us; speedup vs baseline: 2.4137x; 1.3159x over previous
//
#include <hip/hip_runtime.h>

#define B_ 64
#define D_ 512
#define N_ 1200
#define K_ 64
#define NT2CNT 19   // ceil(1200/64) pixel tiles for logits kernels
#define AST 1216    // padded a' row stride (= NT2CNT*64), 38 K-steps of 32
#define NSTEP 38
#define NT3 16      // n-tile for legacy k_vlad (divides 1200: 75 tiles)
#define PT 32       // fused-fallback pixels per tile
#define NTILES 38   // fused-fallback tiles

typedef __attribute__((ext_vector_type(8))) short bf16x8;
typedef __attribute__((ext_vector_type(4))) float f32x4;

__device__ __forceinline__ float bf2f(unsigned short u) {
  union { unsigned int i; float f; } v; v.i = ((unsigned int)u) << 16; return v.f;
}
__device__ __forceinline__ unsigned short f2bf(float f) {
  unsigned int u = __float_as_uint(f);
  u += 0x7FFFu + ((u >> 16) & 1u);   // round-to-nearest-even
  return (unsigned short)(u >> 16);
}

// ---------------- K0: split w into fragment-ordered bf16 hi/lo -------------
__global__ __launch_bounds__(64) void k_wsplit(
    const float* __restrict__ w,
    unsigned short* __restrict__ wfh, unsigned short* __restrict__ wfl)
{
  const int blk = blockIdx.x;
  const int wv = blk >> 4, dstep = blk & 15;
  const int l = threadIdx.x;
  const int row = wv * 16 + (l & 15);
  const int dbase = dstep * 32 + 8 * (l >> 4);
  const size_t o = ((size_t)blk * 64 + l) * 8;
#pragma unroll
  for (int j = 0; j < 8; ++j) {
    const float v = w[row * D_ + dbase + j];
    const unsigned int u = __float_as_uint(v);
    const unsigned int h = u & 0xFFFF0000u;      // truncation: hi is EXACT
    wfh[o + j] = (unsigned short)(h >> 16);
    wfl[o + j] = f2bf(v - __uint_as_float(h));   // residual, RNE to bf16
  }
}

// ---------------- K1 (MFMA): L2norm + logits(3-pass split bf16) + softmax --
// folded=1: a_bf stores bf16(a*invn) with row stride AST, zero-padded tail.
// folded=0: a_bf stores bf16(a) with row stride N_ (legacy k_vlad consumer).
__global__ __launch_bounds__(256) void k_logits_mfma(
    const float* __restrict__ x, const unsigned short* __restrict__ wfh,
    const unsigned short* __restrict__ wfl, unsigned short* __restrict__ a_bf,
    float* __restrict__ invn_ws, float* __restrict__ asum_part, int folded)
{
  const int nt = blockIdx.x, b = blockIdx.y;
  const int n0 = nt * 64;
  const int t = threadIdx.x;
  const int lane = t & 63, wv = t >> 6;

  __shared__ __align__(16) unsigned short xbuf[2][2][64][136];  // 69.6 KB
  __shared__ float nsq_s[4][64];
  __shared__ float red_s[3][64];     // [0]=invn, [1]=max, [2]=1/sum
  float (*ls)[66] = reinterpret_cast<float(*)[66]>(&xbuf[0][0][0][0]);  // overlay

  const int n_l = t & 63, dg = t >> 6;
  const int nc = min(n0 + n_l, N_ - 1);            // clamp ragged tile
  const float* xb = x + (size_t)b * D_ * N_ + nc;
  float nsq = 0.f;

  f32x4 acc[4] = {{0.f,0.f,0.f,0.f},{0.f,0.f,0.f,0.f},{0.f,0.f,0.f,0.f},{0.f,0.f,0.f,0.f}};

  auto conv = [&](int c, int buf) {
    const int db = c * 128 + dg * 32;
#pragma unroll
    for (int i = 0; i < 32; i += 4) {
      const float f0 = xb[(size_t)(db + i + 0) * N_];   // coalesced over n
      const float f1 = xb[(size_t)(db + i + 1) * N_];
      const float f2 = xb[(size_t)(db + i + 2) * N_];
      const float f3 = xb[(size_t)(db + i + 3) * N_];
      nsq += f0 * f0 + f1 * f1 + f2 * f2 + f3 * f3;
      const unsigned int u0 = __float_as_uint(f0), u1 = __float_as_uint(f1);
      const unsigned int u2 = __float_as_uint(f2), u3 = __float_as_uint(f3);
      const unsigned int h0 = u0 & 0xFFFF0000u, h1 = u1 & 0xFFFF0000u;
      const unsigned int h2 = u2 & 0xFFFF0000u, h3 = u3 & 0xFFFF0000u;
      ushort4 hv, lv;
      hv.x = (unsigned short)(h0 >> 16); hv.y = (unsigned short)(h1 >> 16);
      hv.z = (unsigned short)(h2 >> 16); hv.w = (unsigned short)(h3 >> 16);
      lv.x = f2bf(f0 - __uint_as_float(h0)); lv.y = f2bf(f1 - __uint_as_float(h1));
      lv.z = f2bf(f2 - __uint_as_float(h2)); lv.w = f2bf(f3 - __uint_as_float(h3));
      *(ushort4*)&xbuf[buf][0][n_l][dg * 32 + i] = hv;
      *(ushort4*)&xbuf[buf][1][n_l][dg * 32 + i] = lv;
    }
  };

  auto mstep = [&](int c, int buf) {
#pragma unroll
    for (int ds = 0; ds < 4; ++ds) {
      const int fi = (wv * 16 + c * 4 + ds) * 64 + lane;
      const bf16x8 ah = ((const bf16x8*)wfh)[fi];   // coalesced 16B/lane (L2-hot)
      const bf16x8 al = ((const bf16x8*)wfl)[fi];
#pragma unroll
      for (int s = 0; s < 4; ++s) {
        const unsigned short* ph = &xbuf[buf][0][s * 16 + (lane & 15)][ds * 32 + 8 * (lane >> 4)];
        const unsigned short* pl = &xbuf[buf][1][s * 16 + (lane & 15)][ds * 32 + 8 * (lane >> 4)];
        const bf16x8 bh = *(const bf16x8*)ph;       // ds_read_b128, conflict-free
        const bf16x8 bl = *(const bf16x8*)pl;
        acc[s] = __builtin_amdgcn_mfma_f32_16x16x32_bf16(ah, bh, acc[s], 0, 0, 0);
        acc[s] = __builtin_amdgcn_mfma_f32_16x16x32_bf16(al, bh, acc[s], 0, 0, 0);
        acc[s] = __builtin_amdgcn_mfma_f32_16x16x32_bf16(ah, bl, acc[s], 0, 0, 0);
      }
    }
  };

  conv(0, 0);
  __syncthreads();
  for (int c = 0; c < 4; ++c) {
    if (c < 3) conv(c + 1, (c + 1) & 1);
    mstep(c, c & 1);
    __syncthreads();
  }

  nsq_s[dg][n_l] = nsq;
  __syncthreads();
  if (t < 64) {
    const float s4 = nsq_s[0][t] + nsq_s[1][t] + nsq_s[2][t] + nsq_s[3][t];
    const float inv = 1.f / fmaxf(sqrtf(s4), 1e-12f);
    red_s[0][t] = inv;
    if (n0 + t < N_) invn_ws[b * N_ + n0 + t] = inv;
  }
  __syncthreads();

  // C/D layout (verified): n = 16s + (lane&15), k = 16wv + 4*(lane>>4) + r
#pragma unroll
  for (int s = 0; s < 4; ++s) {
    const int n = 16 * s + (lane & 15);
    const float inv = red_s[0][n];
#pragma unroll
    for (int r = 0; r < 4; ++r) {
      const int k = 16 * wv + 4 * (lane >> 4) + r;
      ls[k][n] = acc[s][r] * inv;
    }
  }
  __syncthreads();

  if (t < 64) {
    float m = -1e30f;
    for (int k = 0; k < K_; ++k) m = fmaxf(m, ls[k][t]);
    float ssum = 0.f;
    for (int k = 0; k < K_; ++k) ssum += __expf(ls[k][t] - m);
    red_s[1][t] = m;
    red_s[2][t] = 1.f / ssum;
  }
  __syncthreads();

#pragma unroll
  for (int s = 0; s < 4; ++s) {
    const int n = 16 * s + (lane & 15);
    const bool valid = (n0 + n) < N_;
    const float inv = red_s[0][n], mv = red_s[1][n], si = red_s[2][n];
#pragma unroll
    for (int r = 0; r < 4; ++r) {
      const int k = 16 * wv + 4 * (lane >> 4) + r;
      const float av = valid ? __expf(acc[s][r] * inv - mv) * si : 0.f;
      ls[k][n] = av;                                  // raw a for asum
      if (folded) {
        // padded stride AST, always write (av=0 in pad -> k_vlad_mfma guard-free)
        a_bf[((size_t)b * K_ + k) * AST + n0 + n] = f2bf(av * inv);
      } else if (valid) {
        a_bf[((size_t)b * K_ + k) * N_ + n0 + n] = f2bf(av);
      }
    }
  }
  __syncthreads();

  if (t < K_) {
    float su = 0.f;
#pragma unroll 8
    for (int p = 0; p < 64; ++p) su += ls[t][p];
    asum_part[(b * NT2CNT + nt) * K_ + t] = su;
  }
}

// ---------------- K2 (MFMA): vlad raw PV -> vlad_ws (fp32) ---------------
// grid 256 = b*4 + dc. 4 waves; wave wv owns k-rows 16wv..16wv+15, 128 d.
// a' (bf16, invn folded, zero-padded to AST) x split-bf16 raw x, fp32 acc.
__global__ __launch_bounds__(256) void k_vlad_mfma(
    const float* __restrict__ x, const unsigned short* __restrict__ a_bf,
    float* __restrict__ vlad_ws)
{
  const int id = blockIdx.x;
  const int b  = id >> 2;
  const int dc = id & 3;
  const int t = threadIdx.x;
  const int lane = t & 63, wv = t >> 6;

  __shared__ __align__(16) unsigned short xs[2][2][128][40];  // 40 KB, stride 80B (5x16B: odd)

  f32x4 acc[8];
#pragma unroll
  for (int i = 0; i < 8; ++i) acc[i] = (f32x4){0.f, 0.f, 0.f, 0.f};

  // staging: row sr = t>>1 (0..127), half sh = t&1 (16 n each)
  const int sr = t >> 1, sh = t & 1;
  const float* xrow = x + (size_t)b * D_ * N_ + (size_t)(dc * 128 + sr) * N_;

  auto stage = [&](int s, int buf) {
    const int nb = s * 32 + sh * 16;
#pragma unroll
    for (int i = 0; i < 4; ++i) {
      const int nn = nb + 4 * i;
      float4 v = make_float4(0.f, 0.f, 0.f, 0.f);
      if (nn < N_) v = *(const float4*)(xrow + nn);   // pad tail -> zeros (a'=0 there anyway)
      const unsigned int u0 = __float_as_uint(v.x), u1 = __float_as_uint(v.y);
      const unsigned int u2 = __float_as_uint(v.z), u3 = __float_as_uint(v.w);
      const unsigned int h0 = u0 & 0xFFFF0000u, h1 = u1 & 0xFFFF0000u;
      const unsigned int h2 = u2 & 0xFFFF0000u, h3 = u3 & 0xFFFF0000u;
      ushort4 hv, lv;
      hv.x = (unsigned short)(h0 >> 16); hv.y = (unsigned short)(h1 >> 16);
      hv.z = (unsigned short)(h2 >> 16); hv.w = (unsigned short)(h3 >> 16);
      lv.x = f2bf(v.x - __uint_as_float(h0)); lv.y = f2bf(v.y - __uint_as_float(h1));
      lv.z = f2bf(v.z - __uint_as_float(h2)); lv.w = f2bf(v.w - __uint_as_float(h3));
      *(ushort4*)&xs[buf][0][sr][sh * 16 + 4 * i] = hv;
      *(ushort4*)&xs[buf][1][sr][sh * 16 + 4 * i] = lv;
    }
  };

  const unsigned short* arow =
      a_bf + ((size_t)b * K_ + 16 * wv + (lane & 15)) * AST + 8 * (lane >> 4);

  auto compute = [&](int s, int buf) {
    const bf16x8 af = *(const bf16x8*)(arow + s * 32);   // 16B/lane, L2-hot, no guards (padded)
#pragma unroll
    for (int st = 0; st < 8; ++st) {
      const unsigned short* ph = &xs[buf][0][st * 16 + (lane & 15)][8 * (lane >> 4)];
      const unsigned short* pl = &xs[buf][1][st * 16 + (lane & 15)][8 * (lane >> 4)];
      const bf16x8 bh = *(const bf16x8*)ph;              // ds_read_b128, conflict-free
      const bf16x8 bl = *(const bf16x8*)pl;
      // a * (x_hi + x_lo): x_hi exact truncation, x_lo bf16 residual
      acc[st] = __builtin_amdgcn_mfma_f32_16x16x32_bf16(af, bh, acc[st], 0, 0, 0);
      acc[st] = __builtin_amdgcn_mfma_f32_16x16x32_bf16(af, bl, acc[st], 0, 0, 0);
    }
  };

  stage(0, 0);
  __syncthreads();
  for (int s = 0; s < NSTEP; ++s) {
    if (s < NSTEP - 1) stage(s + 1, (s + 1) & 1);
    compute(s, s & 1);
    __syncthreads();
  }

  // C/D layout: col(d) = 16st + (lane&15), row(k) = 16wv + 4*(lane>>4) + r
  const size_t kb = (size_t)b * K_ + 16 * wv + 4 * (lane >> 4);
  const int db = dc * 128 + (lane & 15);
#pragma unroll
  for (int st = 0; st < 8; ++st)
#pragma unroll
    for (int r = 0; r < 4; ++r)
      vlad_ws[(kb + r) * D_ + db + st * 16] = acc[st][r];
}

// ---------------- K3: -asum*c, intra-norm, global(=1/8), fp32 out ---------
__global__ __launch_bounds__(256) void k_norm(
    const float* __restrict__ vlad_ws, const float* __restrict__ asum_part,
    const float* __restrict__ cent, float* __restrict__ out)
{
  const int id = blockIdx.x;        // 512: kg*64 + b
  const int kg = id >> 6;
  const int b  = id & 63;
  const int t  = threadIdx.x;
  __shared__ float asums[8];
  __shared__ float part[8][4];
  __shared__ float scale_s[8];

  if (t < 8) {
    float s = 0.f;
    for (int nt2 = 0; nt2 < NT2CNT; ++nt2)
      s += asum_part[(b * NT2CNT + nt2) * K_ + kg * 8 + t];
    asums[t] = s;
  }
  __syncthreads();

  const int d0 = 2 * t;
  const int lane = t & 63, wv = t >> 6;
  float acc[16];
#pragma unroll
  for (int j = 0; j < 8; ++j) {
    const int k = kg * 8 + j;
    const float2 v  = *(const float2*)(vlad_ws + ((size_t)b * K_ + k) * D_ + d0);
    const float2 c2 = *(const float2*)(cent + (size_t)k * D_ + d0);
    const float asv = asums[j];
    acc[j * 2]     = v.x - asv * c2.x;
    acc[j * 2 + 1] = v.y - asv * c2.y;
    float s = acc[j * 2] * acc[j * 2] + acc[j * 2 + 1] * acc[j * 2 + 1];
#pragma unroll
    for (int o = 32; o > 0; o >>= 1) s += __shfl_down(s, o, 64);
    if (lane == 0) part[j][wv] = s;
  }
  __syncthreads();
  if (t < 8) {
    const float s = part[t][0] + part[t][1] + part[t][2] + part[t][3];
    scale_s[t] = 0.125f / fmaxf(sqrtf(s), 1e-12f);
  }
  __syncthreads();
#pragma unroll
  for (int j = 0; j < 8; ++j) {
    const int k = kg * 8 + j;
    const float f = scale_s[j];
    float2 o;
    o.x = acc[j * 2] * f;
    o.y = acc[j * 2 + 1] * f;
    *(float2*)(out + ((size_t)b * K_ + k) * D_ + d0) = o;
  }
}

// ---------------- Legacy K2 (VALU vlad, r1 fallback) ----------------------
__global__ __launch_bounds__(256) void k_vlad(
    const float* __restrict__ x, const unsigned short* __restrict__ a_bf,
    const float* __restrict__ invn_ws, const float* __restrict__ asum_part,
    const float* __restrict__ cent, float* __restrict__ out)
{
  const int id = blockIdx.x;
  const int kg = id >> 6;
  const int b  = id & 63;
  const int t  = threadIdx.x;
  __shared__ float xs[NT3][518];
  __shared__ float as[8][NT3 + 2];
  __shared__ float asums[8];
  __shared__ float part[8][4];
  __shared__ float scale_s[8];

  if (t < 8) {
    float s = 0.f;
    for (int nt2 = 0; nt2 < NT2CNT; ++nt2)
      s += asum_part[(b * NT2CNT + nt2) * K_ + kg * 8 + t];
    asums[t] = s;
  }
  float acc[16];
#pragma unroll
  for (int i = 0; i < 16; ++i) acc[i] = 0.f;

  const float* xb = x + (size_t)b * D_ * N_;
  const int d0 = 2 * t;
  const int snl = t & 15, sdc = t >> 4;
  const int saj = t >> 4, sanl = t & 15;

  for (int n0 = 0; n0 < N_; n0 += NT3) {
    __syncthreads();
    {
      const float* xp = xb + (size_t)(sdc * 32) * N_ + (n0 + snl);
      float* xrow = &xs[snl][sdc * 32];
#pragma unroll
      for (int i = 0; i < 32; i += 2) {
        float2 w2;
        w2.x = xp[(size_t)i * N_];
        w2.y = xp[(size_t)(i + 1) * N_];
        *(float2*)(xrow + i) = w2;
      }
    }
    if (t < 128) {
      const float av = bf2f(a_bf[((size_t)b * K_ + kg * 8 + saj) * N_ + n0 + sanl])
                     * invn_ws[b * N_ + n0 + sanl];
      as[saj][sanl] = av;
    }
    __syncthreads();
#pragma unroll 2
    for (int nl = 0; nl < NT3; nl += 2) {
      const float2 x0 = *(const float2*)(&xs[nl][d0]);
      const float2 x1 = *(const float2*)(&xs[nl + 1][d0]);
#pragma unroll
      for (int j = 0; j < 8; ++j) {
        const float2 a2 = *(const float2*)(&as[j][nl]);
        acc[j * 2]     = fmaf(a2.x, x0.x, fmaf(a2.y, x1.x, acc[j * 2]));
        acc[j * 2 + 1] = fmaf(a2.x, x0.y, fmaf(a2.y, x1.y, acc[j * 2 + 1]));
      }
    }
  }
  __syncthreads();
  const int lane = t & 63, wv = t >> 6;
#pragma unroll
  for (int j = 0; j < 8; ++j) {
    const int k = kg * 8 + j;
    const float asv = asums[j];
    const float2 c2 = *(const float2*)(cent + (size_t)k * D_ + d0);
    acc[j * 2]     -= asv * c2.x;
    acc[j * 2 + 1] -= asv * c2.y;
    float v = acc[j * 2] * acc[j * 2] + acc[j * 2 + 1] * acc[j * 2 + 1];
#pragma unroll
    for (int o = 32; o > 0; o >>= 1) v += __shfl_down(v, o, 64);
    if (lane == 0) part[j][wv] = v;
  }
  __syncthreads();
  if (t < 8) {
    const float s = part[t][0] + part[t][1] + part[t][2] + part[t][3];
    scale_s[t] = 0.125f / fmaxf(sqrtf(s), 1e-12f);
  }
  __syncthreads();
#pragma unroll
  for (int j = 0; j < 8; ++j) {
    const int k = kg * 8 + j;
    const float f = scale_s[j];
    float2 o;
    o.x = acc[j * 2] * f;
    o.y = acc[j * 2 + 1] * f;
    *(float2*)(out + ((size_t)b * K_ + k) * D_ + d0) = o;
  }
}

// ---------------- Legacy K1 (VALU logits, fallback) -----------------------
__global__ __launch_bounds__(256) void k_logits(
    const float* __restrict__ x, const float* __restrict__ w,
    unsigned short* __restrict__ a_bf, float* __restrict__ invn_ws,
    float* __restrict__ asum_part)
{
  const int nt = blockIdx.x, b = blockIdx.y;
  const int t = threadIdx.x;
  const int px = t & 63;
  const int kg = t >> 6;
  const int n = nt * 64 + px;
  const bool valid = (n < N_);
  const int nc = valid ? n : (N_ - 1);
  __shared__ float lsh[K_][65];

  const float* xb = x + (size_t)b * D_ * N_ + nc;
  const float* wg = w + kg * 16 * D_;

  float acc[16];
#pragma unroll
  for (int j = 0; j < 16; ++j) acc[j] = 0.f;
  float nsq = 0.f;

  for (int d = 0; d < D_; d += 4) {
    const float xv0 = xb[(size_t)(d + 0) * N_];
    const float xv1 = xb[(size_t)(d + 1) * N_];
    const float xv2 = xb[(size_t)(d + 2) * N_];
    const float xv3 = xb[(size_t)(d + 3) * N_];
    nsq += xv0 * xv0 + xv1 * xv1 + xv2 * xv2 + xv3 * xv3;
#pragma unroll
    for (int j = 0; j < 16; ++j) {
      const float4 wv = *(const float4*)(wg + j * D_ + d);
      acc[j] = fmaf(xv0, wv.x, fmaf(xv1, wv.y, fmaf(xv2, wv.z, fmaf(xv3, wv.w, acc[j]))));
    }
  }
  const float invn = 1.f / fmaxf(sqrtf(nsq), 1e-12f);
  if (kg == 0 && valid) invn_ws[b * N_ + n] = invn;
#pragma unroll
  for (int j = 0; j < 16; ++j) lsh[kg * 16 + j][px] = acc[j] * invn;
  __syncthreads();
  float m = -1e30f;
  for (int k = 0; k < K_; ++k) m = fmaxf(m, lsh[k][px]);
  float s = 0.f;
  for (int k = 0; k < K_; ++k) s += __expf(lsh[k][px] - m);
  const float sinv = 1.f / s;
  float av[16];
#pragma unroll
  for (int j = 0; j < 16; ++j)
    av[j] = valid ? __expf(acc[j] * invn - m) * sinv : 0.f;
  __syncthreads();
#pragma unroll
  for (int j = 0; j < 16; ++j) lsh[kg * 16 + j][px] = av[j];
  if (valid) {
#pragma unroll
    for (int j = 0; j < 16; ++j)
      a_bf[((size_t)b * K_ + kg * 16 + j) * N_ + n] = f2bf(av[j]);
  }
  __syncthreads();
  if (t < K_) {
    float su = 0.f;
#pragma unroll 8
    for (int p = 0; p < 64; ++p) su += lsh[t][p];
    asum_part[(b * NT2CNT + nt) * K_ + t] = su;
  }
}

// ---------------- Fallback: fused zero-workspace kernel -------------------
__global__ __launch_bounds__(256) void k_fused(
    const float* __restrict__ x, const float* __restrict__ w,
    const float* __restrict__ cent, float* __restrict__ out)
{
  const int id = blockIdx.x;
  const int kq = id >> 6;
  const int b  = id & 63;
  const int t  = threadIdx.x;
  const int px = t & 31;
  const int kg = t >> 5;
  const bool own = (kg >> 1) == kq;
  const int khbase = (kg & 1) * 8;

  __shared__ unsigned short xs[PT][514];
  __shared__ float ls[K_][33];
  __shared__ float a_s[16][34];
  __shared__ float araw[16][34];
  __shared__ float asums[16];
  __shared__ float part[16][4];
  __shared__ float scale_s[16];

  if (t < 16) asums[t] = 0.f;
  float acc[32];
#pragma unroll
  for (int i = 0; i < 32; ++i) acc[i] = 0.f;
  const float* xb = x + (size_t)b * D_ * N_;

  for (int tile = 0; tile < NTILES; ++tile) {
    const int n0 = tile * PT;
    {
      const int row = t & 31, chunk = t >> 5;
      const int n = n0 + row;
      const int nc = (n < N_) ? n : (N_ - 1);
      const float* xp = xb + (size_t)(chunk * 64) * N_ + nc;
#pragma unroll
      for (int i = 0; i < 64; ++i)
        xs[row][chunk * 64 + i] = f2bf(xp[(size_t)i * N_]);
    }
    __syncthreads();
    float invn;
    {
      const ushort2* xr = (const ushort2*)xs[px];
      float lg[8] = {0,0,0,0,0,0,0,0};
      float nsq = 0.f;
      const float* wbase = w + (size_t)(kg * 8) * D_;
      for (int du = 0; du < D_ / 4; ++du) {
        const ushort2 p0 = xr[2 * du], p1 = xr[2 * du + 1];
        const float x0 = bf2f(p0.x), x1 = bf2f(p0.y), x2 = bf2f(p1.x), x3 = bf2f(p1.y);
        nsq += x0 * x0 + x1 * x1 + x2 * x2 + x3 * x3;
#pragma unroll
        for (int j = 0; j < 8; ++j) {
          const float4 wv = *(const float4*)(wbase + j * D_ + 4 * du);
          lg[j] = fmaf(x0,wv.x,fmaf(x1,wv.y,fmaf(x2,wv.z,fmaf(x3,wv.w,lg[j]))));
        }
      }
      invn = 1.f / fmaxf(sqrtf(nsq), 1e-12f);
#pragma unroll
      for (int j = 0; j < 8; ++j) ls[kg * 8 + j][px] = lg[j] * invn;
    }
    __syncthreads();
    {
      const bool valid = (n0 + px) < N_;
      float m = -1e30f;
      for (int k = 0; k < K_; ++k) m = fmaxf(m, ls[k][px]);
      float s = 0.f;
      for (int k = 0; k < K_; ++k) s += __expf(ls[k][px] - m);
      const float sinv = 1.f / s;
      if (own) {
#pragma unroll
        for (int j = 0; j < 8; ++j) {
          const float av = valid ? __expf(ls[kg * 8 + j][px] - m) * sinv : 0.f;
          araw[khbase + j][px] = av;
          a_s[khbase + j][px]  = av * invn;
        }
      }
    }
    __syncthreads();
    if (t < 16) {
      float su = 0.f;
#pragma unroll 8
      for (int p = 0; p < PT; ++p) su += araw[t][p];
      asums[t] += su;
    }
    {
#pragma unroll 2
      for (int nl = 0; nl < PT; nl += 2) {
        const ushort2 u0 = ((const ushort2*)xs[nl])[t];
        const ushort2 u1 = ((const ushort2*)xs[nl + 1])[t];
        const float x00 = bf2f(u0.x), x01 = bf2f(u0.y);
        const float x10 = bf2f(u1.x), x11 = bf2f(u1.y);
#pragma unroll
        for (int kh = 0; kh < 16; ++kh) {
          const float2 a2 = *(const float2*)(&a_s[kh][nl]);
          acc[kh * 2]     = fmaf(a2.x, x00, fmaf(a2.y, x10, acc[kh * 2]));
          acc[kh * 2 + 1] = fmaf(a2.x, x01, fmaf(a2.y, x11, acc[kh * 2 + 1]));
        }
      }
    }
    __syncthreads();
  }
  const int d0 = 2 * t;
  const int lane = t & 63, wv = t >> 6;
#pragma unroll
  for (int kh = 0; kh < 16; ++kh) {
    const int k = kq * 16 + kh;
    const float asv = asums[kh];
    const float2 c2 = *(const float2*)(cent + (size_t)k * D_ + d0);
    acc[kh * 2]     -= asv * c2.x;
    acc[kh * 2 + 1] -= asv * c2.y;
    float v = acc[kh * 2] * acc[kh * 2] + acc[kh * 2 + 1] * acc[kh * 2 + 1];
#pragma unroll
    for (int o = 32; o > 0; o >>= 1) v += __shfl_down(v, o, 64);
    if (lane == 0) part[kh][wv] = v;
  }
  __syncthreads();
  if (t < 16) {
    const float s = part[t][0] + part[t][1] + part[t][2] + part[t][3];
    scale_s[t] = 0.125f / fmaxf(sqrtf(s), 1e-12f);
  }
  __syncthreads();
#pragma unroll
  for (int kh = 0; kh < 16; ++kh) {
    const int k = kq * 16 + kh;
    const float f = scale_s[kh];
    float2 o;
    o.x = acc[kh * 2] * f;
    o.y = acc[kh * 2 + 1] * f;
    *(float2*)(out + ((size_t)b * K_ + k) * D_ + d0) = o;
  }
}

extern "C" void kernel_launch(void* const* d_in, const int* in_sizes, int n_in,
                              void* d_out, int out_size, void* d_ws, size_t ws_size,
                              hipStream_t stream)
{
  const float* x  = (const float*)d_in[0];   // (B,D,H,W) fp32
  const float* w  = (const float*)d_in[1];   // (K,D) fp32
  const float* ct = (const float*)d_in[2];   // (K,D) fp32
  float* out = (float*)d_out;                // (B, K*D) fp32

  const size_t wf_u16  = (size_t)K_ * D_;            // 32,768 per hi/lo array
  const size_t invn_f  = (size_t)B_ * N_;            // 76,800 floats
  const size_t asum_f  = (size_t)B_ * NT2CNT * K_;   // 77,824 floats
  const size_t a_u16   = (size_t)B_ * K_ * N_;       // unpadded a
  const size_t ap_u16  = (size_t)B_ * K_ * AST;      // padded a'
  const size_t vlad_f  = (size_t)B_ * K_ * D_;       // 2,097,152 floats
  const size_t need_old  = (invn_f + asum_f) * 4 + a_u16 * 2;      // ~10.4 MB
  const size_t need_mfma = need_old + wf_u16 * 2 * 2;              // ~10.5 MB
  const size_t need_v2   = wf_u16 * 2 * 2 + ap_u16 * 2
                         + (invn_f + asum_f + vlad_f) * 4;         // ~19.1 MB

  if (ws_size >= need_v2) {
    unsigned short* wfh = (unsigned short*)d_ws;
    unsigned short* wfl = wfh + wf_u16;
    unsigned short* a_bf = wfl + wf_u16;               // padded, stride AST
    float* invn_ws   = (float*)(a_bf + ap_u16);
    float* asum_part = invn_ws + invn_f;
    float* vlad_ws   = asum_part + asum_f;
    hipLaunchKernelGGL(k_wsplit, dim3(64), dim3(64), 0, stream, w, wfh, wfl);
    hipLaunchKernelGGL(k_logits_mfma, dim3(NT2CNT, B_), dim3(256), 0, stream,
                       x, wfh, wfl, a_bf, invn_ws, asum_part, 1);
    hipLaunchKernelGGL(k_vlad_mfma, dim3(256), dim3(256), 0, stream,
                       x, a_bf, vlad_ws);
    hipLaunchKernelGGL(k_norm, dim3(512), dim3(256), 0, stream,
                       vlad_ws, asum_part, ct, out);
  } else if (ws_size >= need_mfma) {
    unsigned short* wfh = (unsigned short*)d_ws;
    unsigned short* wfl = wfh + wf_u16;
    float* invn_ws   = (float*)(wfl + wf_u16);
    float* asum_part = invn_ws + invn_f;
    unsigned short* a_bf = (unsigned short*)(asum_part + asum_f);
    hipLaunchKernelGGL(k_wsplit, dim3(64), dim3(64), 0, stream, w, wfh, wfl);
    hipLaunchKernelGGL(k_logits_mfma, dim3(NT2CNT, B_), dim3(256), 0, stream,
                       x, wfh, wfl, a_bf, invn_ws, asum_part, 0);
    hipLaunchKernelGGL(k_vlad, dim3(512), dim3(256), 0, stream,
                       x, a_bf, invn_ws, asum_part, ct, out);
  } else if (ws_size >= need_old) {
    float* invn_ws   = (float*)d_ws;
    float* asum_part = invn_ws + invn_f;
    unsigned short* a_bf = (unsigned short*)(asum_part + asum_f);
    hipLaunchKernelGGL(k_logits, dim3(NT2CNT, B_), dim3(256), 0, stream,
                       x, w, a_bf, invn_ws, asum_part);
    hipLaunchKernelGGL(k_vlad, dim3(512), dim3(256), 0, stream,
                       x, a_bf, invn_ws, asum_part, ct, out);
  } else {
    hipLaunchKernelGGL(k_fused, dim3(256), dim3(256), 0, stream, x, w, ct, out);
  }
}

// Round 3
// 287.221 us; speedup vs baseline: 2.6271x; 1.0885x over previous
//
#include <hip/hip_runtime.h>

#define B_ 64
#define D_ 512
#define N_ 1200
#define K_ 64
#define NT2CNT 19   // ceil(1200/64) pixel tiles for logits kernels
#define AST 1216    // padded a' row stride (= NT2CNT*64), 38 K-steps of 32
#define NT3 16      // n-tile for legacy k_vlad (divides 1200: 75 tiles)
#define PT 32       // fused-fallback pixels per tile
#define NTILES 38   // fused-fallback tiles

typedef unsigned short u16;
typedef __attribute__((ext_vector_type(8))) short bf16x8;
typedef __attribute__((ext_vector_type(8))) unsigned short u16x8;
typedef __attribute__((ext_vector_type(4))) float f32x4;

__device__ __forceinline__ float bf2f(u16 u) {
  union { unsigned int i; float f; } v; v.i = ((unsigned int)u) << 16; return v.f;
}
__device__ __forceinline__ u16 f2bf(float f) {
  unsigned int u = __float_as_uint(f);
  u += 0x7FFFu + ((u >> 16) & 1u);   // round-to-nearest-even
  return (u16)(u >> 16);
}

// ---------------- K0: split w into fragment-ordered bf16 hi/lo -------------
// frag element j of lane l for (wv,kk): w[16*wv + (l&15)][kk*32 + 8*(l>>4) + j]
__global__ __launch_bounds__(64) void k_wsplit(
    const float* __restrict__ w,
    u16* __restrict__ wfh, u16* __restrict__ wfl)
{
  const int blk = blockIdx.x;
  const int wv = blk >> 4, kk = blk & 15;
  const int l = threadIdx.x;
  const int row = wv * 16 + (l & 15);
  const int dbase = kk * 32 + 8 * (l >> 4);
  const size_t o = ((size_t)blk * 64 + l) * 8;
#pragma unroll
  for (int j = 0; j < 8; ++j) {
    const float v = w[row * D_ + dbase + j];
    const unsigned int u = __float_as_uint(v);
    const unsigned int h = u & 0xFFFF0000u;      // truncation: hi is EXACT
    wfh[o + j] = (u16)(h >> 16);
    wfl[o + j] = f2bf(v - __uint_as_float(h));   // residual, RNE to bf16
  }
}

// ---------------- K1 (MFMA): L2norm + logits(3-pass split bf16) + softmax --
// grid (19, 64), block 256 (4 waves). Wave wv owns k-rows 16wv..16wv+15.
// 8 chunks of 64 d; frag-ordered LDS (16B/slot, conflict-free both sides);
// pipeline: load regs(c+1) -> mstep(c) -> convert+write(c+1) -> sync.
__global__ __launch_bounds__(256, 4) void k_logits_mfma(
    const float* __restrict__ x, const u16* __restrict__ wfh,
    const u16* __restrict__ wfl, u16* __restrict__ a_bf,
    float* __restrict__ invn_ws, float* __restrict__ asum_part, int folded)
{
  const int nt = blockIdx.x, b = blockIdx.y;
  const int n0 = nt * 64;
  const int t = threadIdx.x;
  const int lane = t & 63, wv = t >> 6;

  // [dbuf][hi/lo][slot(kk*256+s*64+lane)][8] : 32 KB total
  __shared__ __align__(16) u16 xbuf[2][2][512][8];
  __shared__ float nsq_s[4][64];
  __shared__ float red_s[3][64];     // [0]=invn, [1]=max, [2]=1/sum
  float (*ls)[66] = reinterpret_cast<float(*)[66]>(&xbuf[0][0][0][0]);  // 16.9 KB overlay

  // converter identity: pixel n_l, 16-d stripe dg per 64-d chunk
  const int n_l = t & 63, dg = t >> 6;
  const int nc = min(n0 + n_l, N_ - 1);            // clamp ragged tile
  const float* xb = x + (size_t)b * D_ * N_ + nc;
  float nsq = 0.f;

  f32x4 acc[4] = {{0.f,0.f,0.f,0.f},{0.f,0.f,0.f,0.f},{0.f,0.f,0.f,0.f},{0.f,0.f,0.f,0.f}};

  const int kkl_w = dg >> 1;           // which K=32 half of the chunk this stripe feeds
  const int qb    = (dg & 1) * 2;      // frag-lane-high base (q = qb, qb+1)
  const int slotw = kkl_w * 256 + (n_l >> 4) * 64 + qb * 16 + (n_l & 15);

  auto loadf = [&](int c, float* f) {
    const int db = c * 64 + dg * 16;
#pragma unroll
    for (int e = 0; e < 16; ++e) f[e] = xb[(size_t)(db + e) * N_];  // coalesced over n
  };
  auto cvtwrite = [&](const float* f, int buf) {
    u16x8 h0{}, h1{}, l0{}, l1{};
#pragma unroll
    for (int e = 0; e < 16; ++e) {
      nsq += f[e] * f[e];
      const unsigned int u = __float_as_uint(f[e]);
      const unsigned int hi = u & 0xFFFF0000u;
      const u16 hh = (u16)(hi >> 16);
      const u16 ll = f2bf(f[e] - __uint_as_float(hi));
      if (e < 8) { h0[e] = (short)hh; l0[e] = (short)ll; }
      else       { h1[e - 8] = (short)hh; l1[e - 8] = (short)ll; }
    }
    *(u16x8*)xbuf[buf][0][slotw]      = h0;   // ds_write_b128, even bank spread
    *(u16x8*)xbuf[buf][0][slotw + 16] = h1;
    *(u16x8*)xbuf[buf][1][slotw]      = l0;
    *(u16x8*)xbuf[buf][1][slotw + 16] = l1;
  };
  auto mstep = [&](int c, int buf) {
#pragma unroll
    for (int kkl = 0; kkl < 2; ++kkl) {
      const int fi = (wv * 16 + c * 2 + kkl) * 64 + lane;
      const bf16x8 ah = ((const bf16x8*)wfh)[fi];   // 16B/lane, L2-hot
      const bf16x8 al = ((const bf16x8*)wfl)[fi];
#pragma unroll
      for (int s = 0; s < 4; ++s) {
        const bf16x8 bh = *(const bf16x8*)xbuf[buf][0][kkl * 256 + s * 64 + lane];
        const bf16x8 bl = *(const bf16x8*)xbuf[buf][1][kkl * 256 + s * 64 + lane];
        // 3-pass fp32-split: hi*hi + lo*hi + hi*lo (lo*lo dropped, <3e-5)
        acc[s] = __builtin_amdgcn_mfma_f32_16x16x32_bf16(ah, bh, acc[s], 0, 0, 0);
        acc[s] = __builtin_amdgcn_mfma_f32_16x16x32_bf16(al, bh, acc[s], 0, 0, 0);
        acc[s] = __builtin_amdgcn_mfma_f32_16x16x32_bf16(ah, bl, acc[s], 0, 0, 0);
      }
    }
  };

  { float f[16]; loadf(0, f); cvtwrite(f, 0); }
  __syncthreads();
#pragma unroll
  for (int c = 0; c < 8; ++c) {
    float f[16];
    if (c < 7) loadf(c + 1, f);        // issue loads early (latency hides under mstep)
    mstep(c, c & 1);
    if (c < 7) cvtwrite(f, (c + 1) & 1);
    __syncthreads();
  }

  nsq_s[dg][n_l] = nsq;
  __syncthreads();
  if (t < 64) {
    const float s4 = nsq_s[0][t] + nsq_s[1][t] + nsq_s[2][t] + nsq_s[3][t];
    const float inv = 1.f / fmaxf(sqrtf(s4), 1e-12f);
    red_s[0][t] = inv;
    if (n0 + t < N_) invn_ws[b * N_ + t + n0] = inv;
  }
  __syncthreads();

  // C/D layout (verified): n = 16s + (lane&15), k = 16wv + 4*(lane>>4) + r
#pragma unroll
  for (int s = 0; s < 4; ++s) {
    const int n = 16 * s + (lane & 15);
    const float inv = red_s[0][n];
#pragma unroll
    for (int r = 0; r < 4; ++r) {
      const int k = 16 * wv + 4 * (lane >> 4) + r;
      ls[k][n] = acc[s][r] * inv;
    }
  }
  __syncthreads();

  if (t < 64) {
    float m = -1e30f;
    for (int k = 0; k < K_; ++k) m = fmaxf(m, ls[k][t]);
    float ssum = 0.f;
    for (int k = 0; k < K_; ++k) ssum += __expf(ls[k][t] - m);
    red_s[1][t] = m;
    red_s[2][t] = 1.f / ssum;
  }
  __syncthreads();

#pragma unroll
  for (int s = 0; s < 4; ++s) {
    const int n = 16 * s + (lane & 15);
    const bool valid = (n0 + n) < N_;
    const float inv = red_s[0][n], mv = red_s[1][n], si = red_s[2][n];
#pragma unroll
    for (int r = 0; r < 4; ++r) {
      const int k = 16 * wv + 4 * (lane >> 4) + r;
      const float av = valid ? __expf(acc[s][r] * inv - mv) * si : 0.f;
      ls[k][n] = av;                                  // raw a for asum
      if (folded) {
        a_bf[((size_t)b * K_ + k) * AST + n0 + n] = f2bf(av * inv);  // pad writes 0
      } else if (valid) {
        a_bf[((size_t)b * K_ + k) * N_ + n0 + n] = f2bf(av);
      }
    }
  }
  __syncthreads();

  if (t < K_) {
    float su = 0.f;
#pragma unroll 8
    for (int p = 0; p < 64; ++p) su += ls[t][p];
    asum_part[(b * NT2CNT + nt) * K_ + t] = su;
  }
}

// ---------------- K2 (MFMA): vlad raw PV -> vlad_ws partials (fp32) -------
// grid 512 = b*8 + dc*2 + ns. 4 waves; wave wv: k-rows 16wv.., 128 d, 19 n-steps.
__global__ __launch_bounds__(256, 4) void k_vlad_mfma(
    const float* __restrict__ x, const u16* __restrict__ a_bf,
    float* __restrict__ vlad_ws)
{
  const int id = blockIdx.x;
  const int b  = id >> 3;
  const int dc = (id >> 1) & 3;
  const int ns = id & 1;
  const int t = threadIdx.x;
  const int lane = t & 63, wv = t >> 6;

  // [dbuf][hi/lo][slot(st*64+lane)][8] : 32 KB
  __shared__ __align__(16) u16 xs[2][2][512][8];

  f32x4 acc[8];
#pragma unroll
  for (int i = 0; i < 8; ++i) acc[i] = (f32x4){0.f, 0.f, 0.f, 0.f};

  const int sr = t >> 1, sh = t & 1;           // d-row, n-half(16)
  const float* xrow = x + (size_t)b * D_ * N_ + (size_t)(dc * 128 + sr) * N_;
  const int slotw = (sr >> 4) * 64 + (sh * 2) * 16 + (sr & 15);

  auto loadf = [&](int s, float4* vr) {
    const int nb = (ns * 19 + s) * 32 + sh * 16;
#pragma unroll
    for (int i = 0; i < 4; ++i) {
      const int nn = nb + 4 * i;
      vr[i] = (nn < N_) ? *(const float4*)(xrow + nn)
                        : make_float4(0.f, 0.f, 0.f, 0.f);   // tail zeros (a'=0 there)
    }
  };
  auto cvtwrite = [&](const float4* vr, int buf) {
    u16x8 h0{}, h1{}, l0{}, l1{};
#pragma unroll
    for (int i = 0; i < 4; ++i) {
      const float fv[4] = {vr[i].x, vr[i].y, vr[i].z, vr[i].w};
#pragma unroll
      for (int j = 0; j < 4; ++j) {
        const int e = 4 * i + j;
        const unsigned int u = __float_as_uint(fv[j]);
        const unsigned int hi = u & 0xFFFF0000u;
        const u16 hh = (u16)(hi >> 16);
        const u16 ll = f2bf(fv[j] - __uint_as_float(hi));
        if (e < 8) { h0[e] = (short)hh; l0[e] = (short)ll; }
        else       { h1[e - 8] = (short)hh; l1[e - 8] = (short)ll; }
      }
    }
    *(u16x8*)xs[buf][0][slotw]      = h0;
    *(u16x8*)xs[buf][0][slotw + 16] = h1;
    *(u16x8*)xs[buf][1][slotw]      = l0;
    *(u16x8*)xs[buf][1][slotw + 16] = l1;
  };

  const u16* arow = a_bf + ((size_t)b * K_ + 16 * wv + (lane & 15)) * AST + 8 * (lane >> 4);

  auto compute = [&](int s, int buf) {
    const bf16x8 af = *(const bf16x8*)(arow + (ns * 19 + s) * 32);  // padded: no guards
#pragma unroll
    for (int st = 0; st < 8; ++st) {
      const bf16x8 bh = *(const bf16x8*)xs[buf][0][st * 64 + lane];
      const bf16x8 bl = *(const bf16x8*)xs[buf][1][st * 64 + lane];
      acc[st] = __builtin_amdgcn_mfma_f32_16x16x32_bf16(af, bh, acc[st], 0, 0, 0);
      acc[st] = __builtin_amdgcn_mfma_f32_16x16x32_bf16(af, bl, acc[st], 0, 0, 0);
    }
  };

  { float4 vr[4]; loadf(0, vr); cvtwrite(vr, 0); }
  __syncthreads();
#pragma unroll 2
  for (int s = 0; s < 19; ++s) {
    float4 vr[4];
    if (s < 18) loadf(s + 1, vr);
    compute(s, s & 1);
    if (s < 18) cvtwrite(vr, (s + 1) & 1);
    __syncthreads();
  }

  // C/D layout: col(d) = 16st + (lane&15), row(k) = 16wv + 4*(lane>>4) + r
  float* vp = vlad_ws + (size_t)ns * B_ * K_ * D_;
  const size_t kb = (size_t)b * K_ + 16 * wv + 4 * (lane >> 4);
  const int db = dc * 128 + (lane & 15);
#pragma unroll
  for (int st = 0; st < 8; ++st)
#pragma unroll
    for (int r = 0; r < 4; ++r)
      vp[(kb + r) * D_ + db + st * 16] = acc[st][r];
}

// ---------------- K3: sum partials, -asum*c, intra-norm, global, out ------
__global__ __launch_bounds__(256) void k_norm(
    const float* __restrict__ vlad_ws, const float* __restrict__ asum_part,
    const float* __restrict__ cent, float* __restrict__ out)
{
  const int id = blockIdx.x;        // 512: kg*64 + b
  const int kg = id >> 6;
  const int b  = id & 63;
  const int t  = threadIdx.x;
  __shared__ float asums[8];
  __shared__ float part[8][4];
  __shared__ float scale_s[8];

  if (t < 8) {
    float s = 0.f;
    for (int nt2 = 0; nt2 < NT2CNT; ++nt2)
      s += asum_part[(b * NT2CNT + nt2) * K_ + kg * 8 + t];
    asums[t] = s;
  }
  __syncthreads();

  const int d0 = 2 * t;
  const int lane = t & 63, wv = t >> 6;
  const size_t vhalf = (size_t)B_ * K_ * D_;
  float acc[16];
#pragma unroll
  for (int j = 0; j < 8; ++j) {
    const int k = kg * 8 + j;
    const size_t vofs = ((size_t)b * K_ + k) * D_ + d0;
    const float2 v0 = *(const float2*)(vlad_ws + vofs);
    const float2 v1 = *(const float2*)(vlad_ws + vhalf + vofs);
    const float2 c2 = *(const float2*)(cent + (size_t)k * D_ + d0);
    const float asv = asums[j];
    acc[j * 2]     = v0.x + v1.x - asv * c2.x;
    acc[j * 2 + 1] = v0.y + v1.y - asv * c2.y;
    float s = acc[j * 2] * acc[j * 2] + acc[j * 2 + 1] * acc[j * 2 + 1];
#pragma unroll
    for (int o = 32; o > 0; o >>= 1) s += __shfl_down(s, o, 64);
    if (lane == 0) part[j][wv] = s;
  }
  __syncthreads();
  if (t < 8) {
    const float s = part[t][0] + part[t][1] + part[t][2] + part[t][3];
    scale_s[t] = 0.125f / fmaxf(sqrtf(s), 1e-12f);
  }
  __syncthreads();
#pragma unroll
  for (int j = 0; j < 8; ++j) {
    const int k = kg * 8 + j;
    const float f = scale_s[j];
    float2 o;
    o.x = acc[j * 2] * f;
    o.y = acc[j * 2 + 1] * f;
    *(float2*)(out + ((size_t)b * K_ + k) * D_ + d0) = o;
  }
}

// ---------------- Legacy K2 (VALU vlad, fallback) -------------------------
__global__ __launch_bounds__(256) void k_vlad(
    const float* __restrict__ x, const u16* __restrict__ a_bf,
    const float* __restrict__ invn_ws, const float* __restrict__ asum_part,
    const float* __restrict__ cent, float* __restrict__ out)
{
  const int id = blockIdx.x;
  const int kg = id >> 6;
  const int b  = id & 63;
  const int t  = threadIdx.x;
  __shared__ float xs[NT3][518];
  __shared__ float as[8][NT3 + 2];
  __shared__ float asums[8];
  __shared__ float part[8][4];
  __shared__ float scale_s[8];

  if (t < 8) {
    float s = 0.f;
    for (int nt2 = 0; nt2 < NT2CNT; ++nt2)
      s += asum_part[(b * NT2CNT + nt2) * K_ + kg * 8 + t];
    asums[t] = s;
  }
  float acc[16];
#pragma unroll
  for (int i = 0; i < 16; ++i) acc[i] = 0.f;

  const float* xb = x + (size_t)b * D_ * N_;
  const int d0 = 2 * t;
  const int snl = t & 15, sdc = t >> 4;
  const int saj = t >> 4, sanl = t & 15;

  for (int n0 = 0; n0 < N_; n0 += NT3) {
    __syncthreads();
    {
      const float* xp = xb + (size_t)(sdc * 32) * N_ + (n0 + snl);
      float* xrow = &xs[snl][sdc * 32];
#pragma unroll
      for (int i = 0; i < 32; i += 2) {
        float2 w2;
        w2.x = xp[(size_t)i * N_];
        w2.y = xp[(size_t)(i + 1) * N_];
        *(float2*)(xrow + i) = w2;
      }
    }
    if (t < 128) {
      const float av = bf2f(a_bf[((size_t)b * K_ + kg * 8 + saj) * N_ + n0 + sanl])
                     * invn_ws[b * N_ + n0 + sanl];
      as[saj][sanl] = av;
    }
    __syncthreads();
#pragma unroll 2
    for (int nl = 0; nl < NT3; nl += 2) {
      const float2 x0 = *(const float2*)(&xs[nl][d0]);
      const float2 x1 = *(const float2*)(&xs[nl + 1][d0]);
#pragma unroll
      for (int j = 0; j < 8; ++j) {
        const float2 a2 = *(const float2*)(&as[j][nl]);
        acc[j * 2]     = fmaf(a2.x, x0.x, fmaf(a2.y, x1.x, acc[j * 2]));
        acc[j * 2 + 1] = fmaf(a2.x, x0.y, fmaf(a2.y, x1.y, acc[j * 2 + 1]));
      }
    }
  }
  __syncthreads();
  const int lane = t & 63, wv = t >> 6;
#pragma unroll
  for (int j = 0; j < 8; ++j) {
    const int k = kg * 8 + j;
    const float asv = asums[j];
    const float2 c2 = *(const float2*)(cent + (size_t)k * D_ + d0);
    acc[j * 2]     -= asv * c2.x;
    acc[j * 2 + 1] -= asv * c2.y;
    float v = acc[j * 2] * acc[j * 2] + acc[j * 2 + 1] * acc[j * 2 + 1];
#pragma unroll
    for (int o = 32; o > 0; o >>= 1) v += __shfl_down(v, o, 64);
    if (lane == 0) part[j][wv] = v;
  }
  __syncthreads();
  if (t < 8) {
    const float s = part[t][0] + part[t][1] + part[t][2] + part[t][3];
    scale_s[t] = 0.125f / fmaxf(sqrtf(s), 1e-12f);
  }
  __syncthreads();
#pragma unroll
  for (int j = 0; j < 8; ++j) {
    const int k = kg * 8 + j;
    const float f = scale_s[j];
    float2 o;
    o.x = acc[j * 2] * f;
    o.y = acc[j * 2 + 1] * f;
    *(float2*)(out + ((size_t)b * K_ + k) * D_ + d0) = o;
  }
}

// ---------------- Legacy K1 (VALU logits, fallback) -----------------------
__global__ __launch_bounds__(256) void k_logits(
    const float* __restrict__ x, const float* __restrict__ w,
    u16* __restrict__ a_bf, float* __restrict__ invn_ws,
    float* __restrict__ asum_part)
{
  const int nt = blockIdx.x, b = blockIdx.y;
  const int t = threadIdx.x;
  const int px = t & 63;
  const int kg = t >> 6;
  const int n = nt * 64 + px;
  const bool valid = (n < N_);
  const int nc = valid ? n : (N_ - 1);
  __shared__ float lsh[K_][65];

  const float* xb = x + (size_t)b * D_ * N_ + nc;
  const float* wg = w + kg * 16 * D_;

  float acc[16];
#pragma unroll
  for (int j = 0; j < 16; ++j) acc[j] = 0.f;
  float nsq = 0.f;

  for (int d = 0; d < D_; d += 4) {
    const float xv0 = xb[(size_t)(d + 0) * N_];
    const float xv1 = xb[(size_t)(d + 1) * N_];
    const float xv2 = xb[(size_t)(d + 2) * N_];
    const float xv3 = xb[(size_t)(d + 3) * N_];
    nsq += xv0 * xv0 + xv1 * xv1 + xv2 * xv2 + xv3 * xv3;
#pragma unroll
    for (int j = 0; j < 16; ++j) {
      const float4 wv = *(const float4*)(wg + j * D_ + d);
      acc[j] = fmaf(xv0, wv.x, fmaf(xv1, wv.y, fmaf(xv2, wv.z, fmaf(xv3, wv.w, acc[j]))));
    }
  }
  const float invn = 1.f / fmaxf(sqrtf(nsq), 1e-12f);
  if (kg == 0 && valid) invn_ws[b * N_ + n] = invn;
#pragma unroll
  for (int j = 0; j < 16; ++j) lsh[kg * 16 + j][px] = acc[j] * invn;
  __syncthreads();
  float m = -1e30f;
  for (int k = 0; k < K_; ++k) m = fmaxf(m, lsh[k][px]);
  float s = 0.f;
  for (int k = 0; k < K_; ++k) s += __expf(lsh[k][px] - m);
  const float sinv = 1.f / s;
  float av[16];
#pragma unroll
  for (int j = 0; j < 16; ++j)
    av[j] = valid ? __expf(acc[j] * invn - m) * sinv : 0.f;
  __syncthreads();
#pragma unroll
  for (int j = 0; j < 16; ++j) lsh[kg * 16 + j][px] = av[j];
  if (valid) {
#pragma unroll
    for (int j = 0; j < 16; ++j)
      a_bf[((size_t)b * K_ + kg * 16 + j) * N_ + n] = f2bf(av[j]);
  }
  __syncthreads();
  if (t < K_) {
    float su = 0.f;
#pragma unroll 8
    for (int p = 0; p < 64; ++p) su += lsh[t][p];
    asum_part[(b * NT2CNT + nt) * K_ + t] = su;
  }
}

// ---------------- Fallback: fused zero-workspace kernel -------------------
__global__ __launch_bounds__(256) void k_fused(
    const float* __restrict__ x, const float* __restrict__ w,
    const float* __restrict__ cent, float* __restrict__ out)
{
  const int id = blockIdx.x;
  const int kq = id >> 6;
  const int b  = id & 63;
  const int t  = threadIdx.x;
  const int px = t & 31;
  const int kg = t >> 5;
  const bool own = (kg >> 1) == kq;
  const int khbase = (kg & 1) * 8;

  __shared__ u16 xs[PT][514];
  __shared__ float ls[K_][33];
  __shared__ float a_s[16][34];
  __shared__ float araw[16][34];
  __shared__ float asums[16];
  __shared__ float part[16][4];
  __shared__ float scale_s[16];

  if (t < 16) asums[t] = 0.f;
  float acc[32];
#pragma unroll
  for (int i = 0; i < 32; ++i) acc[i] = 0.f;
  const float* xb = x + (size_t)b * D_ * N_;

  for (int tile = 0; tile < NTILES; ++tile) {
    const int n0 = tile * PT;
    {
      const int row = t & 31, chunk = t >> 5;
      const int n = n0 + row;
      const int nc = (n < N_) ? n : (N_ - 1);
      const float* xp = xb + (size_t)(chunk * 64) * N_ + nc;
#pragma unroll
      for (int i = 0; i < 64; ++i)
        xs[row][chunk * 64 + i] = f2bf(xp[(size_t)i * N_]);
    }
    __syncthreads();
    float invn;
    {
      const ushort2* xr = (const ushort2*)xs[px];
      float lg[8] = {0,0,0,0,0,0,0,0};
      float nsq = 0.f;
      const float* wbase = w + (size_t)(kg * 8) * D_;
      for (int du = 0; du < D_ / 4; ++du) {
        const ushort2 p0 = xr[2 * du], p1 = xr[2 * du + 1];
        const float x0 = bf2f(p0.x), x1 = bf2f(p0.y), x2 = bf2f(p1.x), x3 = bf2f(p1.y);
        nsq += x0 * x0 + x1 * x1 + x2 * x2 + x3 * x3;
#pragma unroll
        for (int j = 0; j < 8; ++j) {
          const float4 wv = *(const float4*)(wbase + j * D_ + 4 * du);
          lg[j] = fmaf(x0,wv.x,fmaf(x1,wv.y,fmaf(x2,wv.z,fmaf(x3,wv.w,lg[j]))));
        }
      }
      invn = 1.f / fmaxf(sqrtf(nsq), 1e-12f);
#pragma unroll
      for (int j = 0; j < 8; ++j) ls[kg * 8 + j][px] = lg[j] * invn;
    }
    __syncthreads();
    {
      const bool valid = (n0 + px) < N_;
      float m = -1e30f;
      for (int k = 0; k < K_; ++k) m = fmaxf(m, ls[k][px]);
      float s = 0.f;
      for (int k = 0; k < K_; ++k) s += __expf(ls[k][px] - m);
      const float sinv = 1.f / s;
      if (own) {
#pragma unroll
        for (int j = 0; j < 8; ++j) {
          const float av = valid ? __expf(ls[kg * 8 + j][px] - m) * sinv : 0.f;
          araw[khbase + j][px] = av;
          a_s[khbase + j][px]  = av * invn;
        }
      }
    }
    __syncthreads();
    if (t < 16) {
      float su = 0.f;
#pragma unroll 8
      for (int p = 0; p < PT; ++p) su += araw[t][p];
      asums[t] += su;
    }
    {
#pragma unroll 2
      for (int nl = 0; nl < PT; nl += 2) {
        const ushort2 u0 = ((const ushort2*)xs[nl])[t];
        const ushort2 u1 = ((const ushort2*)xs[nl + 1])[t];
        const float x00 = bf2f(u0.x), x01 = bf2f(u0.y);
        const float x10 = bf2f(u1.x), x11 = bf2f(u1.y);
#pragma unroll
        for (int kh = 0; kh < 16; ++kh) {
          const float2 a2 = *(const float2*)(&a_s[kh][nl]);
          acc[kh * 2]     = fmaf(a2.x, x00, fmaf(a2.y, x10, acc[kh * 2]));
          acc[kh * 2 + 1] = fmaf(a2.x, x01, fmaf(a2.y, x11, acc[kh * 2 + 1]));
        }
      }
    }
    __syncthreads();
  }
  const int d0 = 2 * t;
  const int lane = t & 63, wv = t >> 6;
#pragma unroll
  for (int kh = 0; kh < 16; ++kh) {
    const int k = kq * 16 + kh;
    const float asv = asums[kh];
    const float2 c2 = *(const float2*)(cent + (size_t)k * D_ + d0);
    acc[kh * 2]     -= asv * c2.x;
    acc[kh * 2 + 1] -= asv * c2.y;
    float v = acc[kh * 2] * acc[kh * 2] + acc[kh * 2 + 1] * acc[kh * 2 + 1];
#pragma unroll
    for (int o = 32; o > 0; o >>= 1) v += __shfl_down(v, o, 64);
    if (lane == 0) part[kh][wv] = v;
  }
  __syncthreads();
  if (t < 16) {
    const float s = part[t][0] + part[t][1] + part[t][2] + part[t][3];
    scale_s[t] = 0.125f / fmaxf(sqrtf(s), 1e-12f);
  }
  __syncthreads();
#pragma unroll
  for (int kh = 0; kh < 16; ++kh) {
    const int k = kq * 16 + kh;
    const float f = scale_s[kh];
    float2 o;
    o.x = acc[kh * 2] * f;
    o.y = acc[kh * 2 + 1] * f;
    *(float2*)(out + ((size_t)b * K_ + k) * D_ + d0) = o;
  }
}

extern "C" void kernel_launch(void* const* d_in, const int* in_sizes, int n_in,
                              void* d_out, int out_size, void* d_ws, size_t ws_size,
                              hipStream_t stream)
{
  const float* x  = (const float*)d_in[0];   // (B,D,H,W) fp32
  const float* w  = (const float*)d_in[1];   // (K,D) fp32
  const float* ct = (const float*)d_in[2];   // (K,D) fp32
  float* out = (float*)d_out;                // (B, K*D) fp32

  const size_t wf_u16  = (size_t)K_ * D_;            // 32,768 per hi/lo array
  const size_t invn_f  = (size_t)B_ * N_;
  const size_t asum_f  = (size_t)B_ * NT2CNT * K_;
  const size_t a_u16   = (size_t)B_ * K_ * N_;       // unpadded a
  const size_t ap_u16  = (size_t)B_ * K_ * AST;      // padded a'
  const size_t vlad_f  = (size_t)B_ * K_ * D_;       // per partial
  const size_t need_old  = (invn_f + asum_f) * 4 + a_u16 * 2;      // ~10.4 MB
  const size_t need_mfma = need_old + wf_u16 * 2 * 2;              // ~10.5 MB
  const size_t need_v2   = wf_u16 * 2 * 2 + ap_u16 * 2
                         + (invn_f + asum_f + vlad_f * 2) * 4;     // ~27.5 MB

  if (ws_size >= need_v2) {
    u16* wfh = (u16*)d_ws;
    u16* wfl = wfh + wf_u16;
    u16* a_bf = wfl + wf_u16;                          // padded, stride AST
    float* invn_ws   = (float*)(a_bf + ap_u16);
    float* asum_part = invn_ws + invn_f;
    float* vlad_ws   = asum_part + asum_f;             // [2][B][K][D]
    hipLaunchKernelGGL(k_wsplit, dim3(64), dim3(64), 0, stream, w, wfh, wfl);
    hipLaunchKernelGGL(k_logits_mfma, dim3(NT2CNT, B_), dim3(256), 0, stream,
                       x, wfh, wfl, a_bf, invn_ws, asum_part, 1);
    hipLaunchKernelGGL(k_vlad_mfma, dim3(512), dim3(256), 0, stream,
                       x, a_bf, vlad_ws);
    hipLaunchKernelGGL(k_norm, dim3(512), dim3(256), 0, stream,
                       vlad_ws, asum_part, ct, out);
  } else if (ws_size >= need_mfma) {
    u16* wfh = (u16*)d_ws;
    u16* wfl = wfh + wf_u16;
    float* invn_ws   = (float*)(wfl + wf_u16);
    float* asum_part = invn_ws + invn_f;
    u16* a_bf = (u16*)(asum_part + asum_f);
    hipLaunchKernelGGL(k_wsplit, dim3(64), dim3(64), 0, stream, w, wfh, wfl);
    hipLaunchKernelGGL(k_logits_mfma, dim3(NT2CNT, B_), dim3(256), 0, stream,
                       x, wfh, wfl, a_bf, invn_ws, asum_part, 0);
    hipLaunchKernelGGL(k_vlad, dim3(512), dim3(256), 0, stream,
                       x, a_bf, invn_ws, asum_part, ct, out);
  } else if (ws_size >= need_old) {
    float* invn_ws   = (float*)d_ws;
    float* asum_part = invn_ws + invn_f;
    u16* a_bf = (u16*)(asum_part + asum_f);
    hipLaunchKernelGGL(k_logits, dim3(NT2CNT, B_), dim3(256), 0, stream,
                       x, w, a_bf, invn_ws, asum_part);
    hipLaunchKernelGGL(k_vlad, dim3(512), dim3(256), 0, stream,
                       x, a_bf, invn_ws, asum_part, ct, out);
  } else {
    hipLaunchKernelGGL(k_fused, dim3(256), dim3(256), 0, stream, x, w, ct, out);
  }
}

// Round 4
// 286.588 us; speedup vs baseline: 2.6329x; 1.0022x over previous
//
#include <hip/hip_runtime.h>

#define B_ 64
#define D_ 512
#define N_ 1200
#define K_ 64
#define NT2CNT 19   // ceil(1200/64) pixel tiles for logits kernels
#define AST 1216    // padded a' row stride (= NT2CNT*64), 38 K-steps of 32
#define NT3 16      // n-tile for legacy k_vlad (divides 1200: 75 tiles)
#define PT 32       // fused-fallback pixels per tile
#define NTILES 38   // fused-fallback tiles

typedef unsigned short u16;
typedef __attribute__((ext_vector_type(8))) short bf16x8;
typedef __attribute__((ext_vector_type(8))) unsigned short u16x8;
typedef __attribute__((ext_vector_type(4))) float f32x4;

__device__ __forceinline__ float bf2f(u16 u) {
  union { unsigned int i; float f; } v; v.i = ((unsigned int)u) << 16; return v.f;
}
__device__ __forceinline__ u16 f2bf(float f) {
  unsigned int u = __float_as_uint(f);
  u += 0x7FFFu + ((u >> 16) & 1u);   // round-to-nearest-even
  return (u16)(u >> 16);
}

// ---------------- K0: split w into fragment-ordered bf16 hi/lo -------------
// frag element j of lane l for (wv,kk): w[16*wv + (l&15)][kk*32 + 8*(l>>4) + j]
__global__ __launch_bounds__(64) void k_wsplit(
    const float* __restrict__ w,
    u16* __restrict__ wfh, u16* __restrict__ wfl)
{
  const int blk = blockIdx.x;
  const int wv = blk >> 4, kk = blk & 15;
  const int l = threadIdx.x;
  const int row = wv * 16 + (l & 15);
  const int dbase = kk * 32 + 8 * (l >> 4);
  const size_t o = ((size_t)blk * 64 + l) * 8;
#pragma unroll
  for (int j = 0; j < 8; ++j) {
    const float v = w[row * D_ + dbase + j];
    const unsigned int u = __float_as_uint(v);
    const unsigned int h = u & 0xFFFF0000u;      // truncation: hi is EXACT
    wfh[o + j] = (u16)(h >> 16);
    wfl[o + j] = f2bf(v - __uint_as_float(h));   // residual, RNE to bf16
  }
}

// ---------------- K1 (MFMA): L2norm + logits(3-pass split bf16) + softmax --
// grid (19, 64), block 256 (4 waves). Wave wv owns k-rows 16wv..16wv+15.
// 8 chunks of 64 d. Issue schedule per chunk (vmcnt-FIFO-hazard-free):
//   [x(c+1) loads] [mstep(c): w(c) resident, ds_read only]
//   [w(c+2) loads] [cvtwrite x(c+1) -> counted drain] [barrier]
__global__ __launch_bounds__(256, 4) void k_logits_mfma(
    const float* __restrict__ x, const u16* __restrict__ wfh,
    const u16* __restrict__ wfl, u16* __restrict__ a_bf,
    float* __restrict__ invn_ws, float* __restrict__ asum_part, int folded)
{
  const int nt = blockIdx.x, b = blockIdx.y;
  const int n0 = nt * 64;
  const int t = threadIdx.x;
  const int lane = t & 63, wv = t >> 6;

  // [dbuf][hi/lo][slot(kk*256+s*64+lane)][8] : 32 KB total
  __shared__ __align__(16) u16 xbuf[2][2][512][8];
  __shared__ float nsq_s[4][64];
  __shared__ float red_s[3][64];     // [0]=invn, [1]=max, [2]=1/sum
  float (*ls)[66] = reinterpret_cast<float(*)[66]>(&xbuf[0][0][0][0]);  // 16.9 KB overlay

  // converter identity: pixel n_l, 16-d stripe dg per 64-d chunk
  const int n_l = t & 63, dg = t >> 6;
  const int nc = min(n0 + n_l, N_ - 1);            // clamp ragged tile
  const float* xb = x + (size_t)b * D_ * N_ + nc;
  float nsq = 0.f;

  f32x4 acc[4] = {{0.f,0.f,0.f,0.f},{0.f,0.f,0.f,0.f},{0.f,0.f,0.f,0.f},{0.f,0.f,0.f,0.f}};

  const int kkl_w = dg >> 1;
  const int qb    = (dg & 1) * 2;
  const int slotw = kkl_w * 256 + (n_l >> 4) * 64 + qb * 16 + (n_l & 15);

  auto loadf = [&](int c, float* f) {
    const int db = c * 64 + dg * 16;
#pragma unroll
    for (int e = 0; e < 16; ++e) f[e] = xb[(size_t)(db + e) * N_];  // coalesced over n
  };
  auto cvtwrite = [&](const float* f, int buf) {
#pragma unroll
    for (int half = 0; half < 2; ++half) {        // 8-elem halves: lower reg pressure
      u16x8 hv{}, lv{};
#pragma unroll
      for (int e = 0; e < 8; ++e) {
        const float fe = f[half * 8 + e];
        nsq += fe * fe;
        const unsigned int u = __float_as_uint(fe);
        const unsigned int hi = u & 0xFFFF0000u;
        hv[e] = (short)(u16)(hi >> 16);
        lv[e] = (short)f2bf(fe - __uint_as_float(hi));
      }
      *(u16x8*)xbuf[buf][0][slotw + half * 16] = hv;   // ds_write_b128
      *(u16x8*)xbuf[buf][1][slotw + half * 16] = lv;
    }
  };
  auto loadw = [&](int c, bf16x8 (&wf)[2][2]) {
#pragma unroll
    for (int kkl = 0; kkl < 2; ++kkl) {
      const int fi = (wv * 16 + c * 2 + kkl) * 64 + lane;
      wf[kkl][0] = ((const bf16x8*)wfh)[fi];   // 16B/lane, L2-hot
      wf[kkl][1] = ((const bf16x8*)wfl)[fi];
    }
  };
  auto mstep = [&](int buf, const bf16x8 (&wf)[2][2]) {
#pragma unroll
    for (int kkl = 0; kkl < 2; ++kkl)
#pragma unroll
      for (int s = 0; s < 4; ++s) {
        const bf16x8 bh = *(const bf16x8*)xbuf[buf][0][kkl * 256 + s * 64 + lane];
        const bf16x8 bl = *(const bf16x8*)xbuf[buf][1][kkl * 256 + s * 64 + lane];
        // 3-pass fp32-split: hi*hi + lo*hi + hi*lo (lo*lo dropped, <3e-5)
        acc[s] = __builtin_amdgcn_mfma_f32_16x16x32_bf16(wf[kkl][0], bh, acc[s], 0, 0, 0);
        acc[s] = __builtin_amdgcn_mfma_f32_16x16x32_bf16(wf[kkl][1], bh, acc[s], 0, 0, 0);
        acc[s] = __builtin_amdgcn_mfma_f32_16x16x32_bf16(wf[kkl][0], bl, acc[s], 0, 0, 0);
      }
  };

  bf16x8 wfrag[2][2][2];                 // [parity][kkl][hi/lo]
  loadw(0, wfrag[0]);                    // w issued BEFORE any x load
  loadw(1, wfrag[1]);
  { float f[16]; loadf(0, f); cvtwrite(f, 0); }
  __syncthreads();
#pragma unroll
  for (int c = 0; c < 8; ++c) {          // full unroll -> static wfrag[c&1]
    float f[16];
    if (c < 7) loadf(c + 1, f);          // x(c+1) issued first
    mstep(c & 1, wfrag[c & 1]);          // w(c) resident: no vm-wait
    if (c < 6) loadw(c + 2, wfrag[c & 1]);  // w(c+2) after consumption of w(c)
    if (c < 7) cvtwrite(f, (c + 1) & 1); // counted drain; w(c+2) stays in flight
    __syncthreads();
  }

  nsq_s[dg][n_l] = nsq;
  __syncthreads();
  if (t < 64) {
    const float s4 = nsq_s[0][t] + nsq_s[1][t] + nsq_s[2][t] + nsq_s[3][t];
    const float inv = 1.f / fmaxf(sqrtf(s4), 1e-12f);
    red_s[0][t] = inv;
    if (n0 + t < N_) invn_ws[b * N_ + t + n0] = inv;
  }
  __syncthreads();

  // C/D layout (verified): n = 16s + (lane&15), k = 16wv + 4*(lane>>4) + r
#pragma unroll
  for (int s = 0; s < 4; ++s) {
    const int n = 16 * s + (lane & 15);
    const float inv = red_s[0][n];
#pragma unroll
    for (int r = 0; r < 4; ++r) {
      const int k = 16 * wv + 4 * (lane >> 4) + r;
      ls[k][n] = acc[s][r] * inv;
    }
  }
  __syncthreads();

  if (t < 64) {
    float m = -1e30f;
    for (int k = 0; k < K_; ++k) m = fmaxf(m, ls[k][t]);
    float ssum = 0.f;
    for (int k = 0; k < K_; ++k) ssum += __expf(ls[k][t] - m);
    red_s[1][t] = m;
    red_s[2][t] = 1.f / ssum;
  }
  __syncthreads();

#pragma unroll
  for (int s = 0; s < 4; ++s) {
    const int n = 16 * s + (lane & 15);
    const bool valid = (n0 + n) < N_;
    const float inv = red_s[0][n], mv = red_s[1][n], si = red_s[2][n];
#pragma unroll
    for (int r = 0; r < 4; ++r) {
      const int k = 16 * wv + 4 * (lane >> 4) + r;
      const float av = valid ? __expf(acc[s][r] * inv - mv) * si : 0.f;
      ls[k][n] = av;                                  // raw a for asum
      if (folded) {
        a_bf[((size_t)b * K_ + k) * AST + n0 + n] = f2bf(av * inv);  // pad writes 0
      } else if (valid) {
        a_bf[((size_t)b * K_ + k) * N_ + n0 + n] = f2bf(av);
      }
    }
  }
  __syncthreads();

  if (t < K_) {
    float su = 0.f;
#pragma unroll 8
    for (int p = 0; p < 64; ++p) su += ls[t][p];
    asum_part[(b * NT2CNT + nt) * K_ + t] = su;
  }
}

// ---------------- K2 (MFMA): vlad raw PV -> vlad_ws partials (fp32) -------
// grid 1024 = b*16 + dc*4 + ns. 4 waves; wave wv: k-rows 16wv.., 128 d.
// n-splits of 10/10/10/8 steps (even). Same FIFO-hazard-free issue order.
__global__ __launch_bounds__(256, 4) void k_vlad_mfma(
    const float* __restrict__ x, const u16* __restrict__ a_bf,
    float* __restrict__ vlad_ws)
{
  const int id = blockIdx.x;
  const int b  = id >> 4;
  const int dc = (id >> 2) & 3;
  const int ns = id & 3;
  const int s0 = ns * 10;
  const int s1 = (ns == 3) ? 38 : s0 + 10;
  const int sl = s1 - 1;
  const int m  = s1 - s0;                    // 10 or 8 (even)
  const int t = threadIdx.x;
  const int lane = t & 63, wv = t >> 6;

  // [dbuf][hi/lo][slot(st*64+lane)][8] : 32 KB
  __shared__ __align__(16) u16 xs[2][2][512][8];

  f32x4 acc[8];
#pragma unroll
  for (int i = 0; i < 8; ++i) acc[i] = (f32x4){0.f, 0.f, 0.f, 0.f};

  const int sr = t >> 1, sh = t & 1;           // d-row, n-half(16)
  const float* xrow = x + (size_t)b * D_ * N_ + (size_t)(dc * 128 + sr) * N_;
  const int slotw = (sr >> 4) * 64 + (sh * 2) * 16 + (sr & 15);

  auto loadf = [&](int s, float4* vr) {
    const int nb = s * 32 + sh * 16;
#pragma unroll
    for (int i = 0; i < 4; ++i) {
      const int nn = nb + 4 * i;
      vr[i] = (nn < N_) ? *(const float4*)(xrow + nn)
                        : make_float4(0.f, 0.f, 0.f, 0.f);   // tail zeros (a'=0 there)
    }
  };
  auto cvtwrite = [&](const float4* vr, int buf) {
#pragma unroll
    for (int half = 0; half < 2; ++half) {
      u16x8 hv{}, lv{};
#pragma unroll
      for (int i = 0; i < 2; ++i) {
        const float4 v = vr[half * 2 + i];
        const float fv[4] = {v.x, v.y, v.z, v.w};
#pragma unroll
        for (int j = 0; j < 4; ++j) {
          const unsigned int u = __float_as_uint(fv[j]);
          const unsigned int hi = u & 0xFFFF0000u;
          hv[i * 4 + j] = (short)(u16)(hi >> 16);
          lv[i * 4 + j] = (short)f2bf(fv[j] - __uint_as_float(hi));
        }
      }
      *(u16x8*)xs[buf][0][slotw + half * 16] = hv;
      *(u16x8*)xs[buf][1][slotw + half * 16] = lv;
    }
  };

  const u16* arow = a_bf + ((size_t)b * K_ + 16 * wv + (lane & 15)) * AST + 8 * (lane >> 4);
  auto loadA = [&](int s) -> bf16x8 { return *(const bf16x8*)(arow + s * 32); };

  auto compute = [&](const bf16x8& af, int buf) {
#pragma unroll
    for (int st = 0; st < 8; ++st) {
      const bf16x8 bh = *(const bf16x8*)xs[buf][0][st * 64 + lane];
      const bf16x8 bl = *(const bf16x8*)xs[buf][1][st * 64 + lane];
      acc[st] = __builtin_amdgcn_mfma_f32_16x16x32_bf16(af, bh, acc[st], 0, 0, 0);
      acc[st] = __builtin_amdgcn_mfma_f32_16x16x32_bf16(af, bl, acc[st], 0, 0, 0);
    }
  };

  // body(s): [x(s+1)] [compute(s): af resident] [af(s+2)] [cvtwrite] [barrier]
  auto body = [&](int s, bf16x8& af, int br) {
    float4 vr[4];
    loadf(min(s + 1, sl), vr);
    compute(af, br);
    af = loadA(min(s + 2, sl));
    cvtwrite(vr, br ^ 1);
    __syncthreads();
  };

  bf16x8 afA = loadA(s0);                     // af issued BEFORE any x load
  bf16x8 afB = loadA(min(s0 + 1, sl));
  { float4 vr[4]; loadf(s0, vr); cvtwrite(vr, 0); }
  __syncthreads();
  for (int j = 0; j < m; j += 2) {            // even/odd bodies: static reg sets
    body(s0 + j, afA, 0);
    body(s0 + j + 1, afB, 1);
  }

  // C/D layout: col(d) = 16st + (lane&15), row(k) = 16wv + 4*(lane>>4) + r
  float* vp = vlad_ws + (size_t)ns * B_ * K_ * D_;
  const size_t kb = (size_t)b * K_ + 16 * wv + 4 * (lane >> 4);
  const int db = dc * 128 + (lane & 15);
#pragma unroll
  for (int st = 0; st < 8; ++st)
#pragma unroll
    for (int r = 0; r < 4; ++r)
      vp[(kb + r) * D_ + db + st * 16] = acc[st][r];
}

// ---------------- K3: sum 4 partials, -asum*c, intra-norm, global, out ----
__global__ __launch_bounds__(256) void k_norm(
    const float* __restrict__ vlad_ws, const float* __restrict__ asum_part,
    const float* __restrict__ cent, float* __restrict__ out)
{
  const int id = blockIdx.x;        // 512: kg*64 + b
  const int kg = id >> 6;
  const int b  = id & 63;
  const int t  = threadIdx.x;
  __shared__ float asums[8];
  __shared__ float part[8][4];
  __shared__ float scale_s[8];

  if (t < 8) {
    float s = 0.f;
    for (int nt2 = 0; nt2 < NT2CNT; ++nt2)
      s += asum_part[(b * NT2CNT + nt2) * K_ + kg * 8 + t];
    asums[t] = s;
  }
  __syncthreads();

  const int d0 = 2 * t;
  const int lane = t & 63, wv = t >> 6;
  const size_t vstride = (size_t)B_ * K_ * D_;
  float acc[16];
#pragma unroll
  for (int j = 0; j < 8; ++j) {
    const int k = kg * 8 + j;
    const size_t vofs = ((size_t)b * K_ + k) * D_ + d0;
    float2 vs = {0.f, 0.f};
#pragma unroll
    for (int p = 0; p < 4; ++p) {
      const float2 v = *(const float2*)(vlad_ws + p * vstride + vofs);
      vs.x += v.x; vs.y += v.y;
    }
    const float2 c2 = *(const float2*)(cent + (size_t)k * D_ + d0);
    const float asv = asums[j];
    acc[j * 2]     = vs.x - asv * c2.x;
    acc[j * 2 + 1] = vs.y - asv * c2.y;
    float s = acc[j * 2] * acc[j * 2] + acc[j * 2 + 1] * acc[j * 2 + 1];
#pragma unroll
    for (int o = 32; o > 0; o >>= 1) s += __shfl_down(s, o, 64);
    if (lane == 0) part[j][wv] = s;
  }
  __syncthreads();
  if (t < 8) {
    const float s = part[t][0] + part[t][1] + part[t][2] + part[t][3];
    scale_s[t] = 0.125f / fmaxf(sqrtf(s), 1e-12f);
  }
  __syncthreads();
#pragma unroll
  for (int j = 0; j < 8; ++j) {
    const int k = kg * 8 + j;
    const float f = scale_s[j];
    float2 o;
    o.x = acc[j * 2] * f;
    o.y = acc[j * 2 + 1] * f;
    *(float2*)(out + ((size_t)b * K_ + k) * D_ + d0) = o;
  }
}

// ---------------- Legacy K2 (VALU vlad, fallback) -------------------------
__global__ __launch_bounds__(256) void k_vlad(
    const float* __restrict__ x, const u16* __restrict__ a_bf,
    const float* __restrict__ invn_ws, const float* __restrict__ asum_part,
    const float* __restrict__ cent, float* __restrict__ out)
{
  const int id = blockIdx.x;
  const int kg = id >> 6;
  const int b  = id & 63;
  const int t  = threadIdx.x;
  __shared__ float xs[NT3][518];
  __shared__ float as[8][NT3 + 2];
  __shared__ float asums[8];
  __shared__ float part[8][4];
  __shared__ float scale_s[8];

  if (t < 8) {
    float s = 0.f;
    for (int nt2 = 0; nt2 < NT2CNT; ++nt2)
      s += asum_part[(b * NT2CNT + nt2) * K_ + kg * 8 + t];
    asums[t] = s;
  }
  float acc[16];
#pragma unroll
  for (int i = 0; i < 16; ++i) acc[i] = 0.f;

  const float* xb = x + (size_t)b * D_ * N_;
  const int d0 = 2 * t;
  const int snl = t & 15, sdc = t >> 4;
  const int saj = t >> 4, sanl = t & 15;

  for (int n0 = 0; n0 < N_; n0 += NT3) {
    __syncthreads();
    {
      const float* xp = xb + (size_t)(sdc * 32) * N_ + (n0 + snl);
      float* xrow = &xs[snl][sdc * 32];
#pragma unroll
      for (int i = 0; i < 32; i += 2) {
        float2 w2;
        w2.x = xp[(size_t)i * N_];
        w2.y = xp[(size_t)(i + 1) * N_];
        *(float2*)(xrow + i) = w2;
      }
    }
    if (t < 128) {
      const float av = bf2f(a_bf[((size_t)b * K_ + kg * 8 + saj) * N_ + n0 + sanl])
                     * invn_ws[b * N_ + n0 + sanl];
      as[saj][sanl] = av;
    }
    __syncthreads();
#pragma unroll 2
    for (int nl = 0; nl < NT3; nl += 2) {
      const float2 x0 = *(const float2*)(&xs[nl][d0]);
      const float2 x1 = *(const float2*)(&xs[nl + 1][d0]);
#pragma unroll
      for (int j = 0; j < 8; ++j) {
        const float2 a2 = *(const float2*)(&as[j][nl]);
        acc[j * 2]     = fmaf(a2.x, x0.x, fmaf(a2.y, x1.x, acc[j * 2]));
        acc[j * 2 + 1] = fmaf(a2.x, x0.y, fmaf(a2.y, x1.y, acc[j * 2 + 1]));
      }
    }
  }
  __syncthreads();
  const int lane = t & 63, wv = t >> 6;
#pragma unroll
  for (int j = 0; j < 8; ++j) {
    const int k = kg * 8 + j;
    const float asv = asums[j];
    const float2 c2 = *(const float2*)(cent + (size_t)k * D_ + d0);
    acc[j * 2]     -= asv * c2.x;
    acc[j * 2 + 1] -= asv * c2.y;
    float v = acc[j * 2] * acc[j * 2] + acc[j * 2 + 1] * acc[j * 2 + 1];
#pragma unroll
    for (int o = 32; o > 0; o >>= 1) v += __shfl_down(v, o, 64);
    if (lane == 0) part[j][wv] = v;
  }
  __syncthreads();
  if (t < 8) {
    const float s = part[t][0] + part[t][1] + part[t][2] + part[t][3];
    scale_s[t] = 0.125f / fmaxf(sqrtf(s), 1e-12f);
  }
  __syncthreads();
#pragma unroll
  for (int j = 0; j < 8; ++j) {
    const int k = kg * 8 + j;
    const float f = scale_s[j];
    float2 o;
    o.x = acc[j * 2] * f;
    o.y = acc[j * 2 + 1] * f;
    *(float2*)(out + ((size_t)b * K_ + k) * D_ + d0) = o;
  }
}

// ---------------- Legacy K1 (VALU logits, fallback) -----------------------
__global__ __launch_bounds__(256) void k_logits(
    const float* __restrict__ x, const float* __restrict__ w,
    u16* __restrict__ a_bf, float* __restrict__ invn_ws,
    float* __restrict__ asum_part)
{
  const int nt = blockIdx.x, b = blockIdx.y;
  const int t = threadIdx.x;
  const int px = t & 63;
  const int kg = t >> 6;
  const int n = nt * 64 + px;
  const bool valid = (n < N_);
  const int nc = valid ? n : (N_ - 1);
  __shared__ float lsh[K_][65];

  const float* xb = x + (size_t)b * D_ * N_ + nc;
  const float* wg = w + kg * 16 * D_;

  float acc[16];
#pragma unroll
  for (int j = 0; j < 16; ++j) acc[j] = 0.f;
  float nsq = 0.f;

  for (int d = 0; d < D_; d += 4) {
    const float xv0 = xb[(size_t)(d + 0) * N_];
    const float xv1 = xb[(size_t)(d + 1) * N_];
    const float xv2 = xb[(size_t)(d + 2) * N_];
    const float xv3 = xb[(size_t)(d + 3) * N_];
    nsq += xv0 * xv0 + xv1 * xv1 + xv2 * xv2 + xv3 * xv3;
#pragma unroll
    for (int j = 0; j < 16; ++j) {
      const float4 wv = *(const float4*)(wg + j * D_ + d);
      acc[j] = fmaf(xv0, wv.x, fmaf(xv1, wv.y, fmaf(xv2, wv.z, fmaf(xv3, wv.w, acc[j]))));
    }
  }
  const float invn = 1.f / fmaxf(sqrtf(nsq), 1e-12f);
  if (kg == 0 && valid) invn_ws[b * N_ + n] = invn;
#pragma unroll
  for (int j = 0; j < 16; ++j) lsh[kg * 16 + j][px] = acc[j] * invn;
  __syncthreads();
  float m = -1e30f;
  for (int k = 0; k < K_; ++k) m = fmaxf(m, lsh[k][px]);
  float s = 0.f;
  for (int k = 0; k < K_; ++k) s += __expf(lsh[k][px] - m);
  const float sinv = 1.f / s;
  float av[16];
#pragma unroll
  for (int j = 0; j < 16; ++j)
    av[j] = valid ? __expf(acc[j] * invn - m) * sinv : 0.f;
  __syncthreads();
#pragma unroll
  for (int j = 0; j < 16; ++j) lsh[kg * 16 + j][px] = av[j];
  if (valid) {
#pragma unroll
    for (int j = 0; j < 16; ++j)
      a_bf[((size_t)b * K_ + kg * 16 + j) * N_ + n] = f2bf(av[j]);
  }
  __syncthreads();
  if (t < K_) {
    float su = 0.f;
#pragma unroll 8
    for (int p = 0; p < 64; ++p) su += lsh[t][p];
    asum_part[(b * NT2CNT + nt) * K_ + t] = su;
  }
}

// ---------------- Fallback: fused zero-workspace kernel -------------------
__global__ __launch_bounds__(256) void k_fused(
    const float* __restrict__ x, const float* __restrict__ w,
    const float* __restrict__ cent, float* __restrict__ out)
{
  const int id = blockIdx.x;
  const int kq = id >> 6;
  const int b  = id & 63;
  const int t  = threadIdx.x;
  const int px = t & 31;
  const int kg = t >> 5;
  const bool own = (kg >> 1) == kq;
  const int khbase = (kg & 1) * 8;

  __shared__ u16 xs[PT][514];
  __shared__ float ls[K_][33];
  __shared__ float a_s[16][34];
  __shared__ float araw[16][34];
  __shared__ float asums[16];
  __shared__ float part[16][4];
  __shared__ float scale_s[16];

  if (t < 16) asums[t] = 0.f;
  float acc[32];
#pragma unroll
  for (int i = 0; i < 32; ++i) acc[i] = 0.f;
  const float* xb = x + (size_t)b * D_ * N_;

  for (int tile = 0; tile < NTILES; ++tile) {
    const int n0 = tile * PT;
    {
      const int row = t & 31, chunk = t >> 5;
      const int n = n0 + row;
      const int nc = (n < N_) ? n : (N_ - 1);
      const float* xp = xb + (size_t)(chunk * 64) * N_ + nc;
#pragma unroll
      for (int i = 0; i < 64; ++i)
        xs[row][chunk * 64 + i] = f2bf(xp[(size_t)i * N_]);
    }
    __syncthreads();
    float invn;
    {
      const ushort2* xr = (const ushort2*)xs[px];
      float lg[8] = {0,0,0,0,0,0,0,0};
      float nsq = 0.f;
      const float* wbase = w + (size_t)(kg * 8) * D_;
      for (int du = 0; du < D_ / 4; ++du) {
        const ushort2 p0 = xr[2 * du], p1 = xr[2 * du + 1];
        const float x0 = bf2f(p0.x), x1 = bf2f(p0.y), x2 = bf2f(p1.x), x3 = bf2f(p1.y);
        nsq += x0 * x0 + x1 * x1 + x2 * x2 + x3 * x3;
#pragma unroll
        for (int j = 0; j < 8; ++j) {
          const float4 wv = *(const float4*)(wbase + j * D_ + 4 * du);
          lg[j] = fmaf(x0,wv.x,fmaf(x1,wv.y,fmaf(x2,wv.z,fmaf(x3,wv.w,lg[j]))));
        }
      }
      invn = 1.f / fmaxf(sqrtf(nsq), 1e-12f);
#pragma unroll
      for (int j = 0; j < 8; ++j) ls[kg * 8 + j][px] = lg[j] * invn;
    }
    __syncthreads();
    {
      const bool valid = (n0 + px) < N_;
      float m = -1e30f;
      for (int k = 0; k < K_; ++k) m = fmaxf(m, ls[k][px]);
      float s = 0.f;
      for (int k = 0; k < K_; ++k) s += __expf(ls[k][px] - m);
      const float sinv = 1.f / s;
      if (own) {
#pragma unroll
        for (int j = 0; j < 8; ++j) {
          const float av = valid ? __expf(ls[kg * 8 + j][px] - m) * sinv : 0.f;
          araw[khbase + j][px] = av;
          a_s[khbase + j][px]  = av * invn;
        }
      }
    }
    __syncthreads();
    if (t < 16) {
      float su = 0.f;
#pragma unroll 8
      for (int p = 0; p < PT; ++p) su += araw[t][p];
      asums[t] += su;
    }
    {
#pragma unroll 2
      for (int nl = 0; nl < PT; nl += 2) {
        const ushort2 u0 = ((const ushort2*)xs[nl])[t];
        const ushort2 u1 = ((const ushort2*)xs[nl + 1])[t];
        const float x00 = bf2f(u0.x), x01 = bf2f(u0.y);
        const float x10 = bf2f(u1.x), x11 = bf2f(u1.y);
#pragma unroll
        for (int kh = 0; kh < 16; ++kh) {
          const float2 a2 = *(const float2*)(&a_s[kh][nl]);
          acc[kh * 2]     = fmaf(a2.x, x00, fmaf(a2.y, x10, acc[kh * 2]));
          acc[kh * 2 + 1] = fmaf(a2.x, x01, fmaf(a2.y, x11, acc[kh * 2 + 1]));
        }
      }
    }
    __syncthreads();
  }
  const int d0 = 2 * t;
  const int lane = t & 63, wv = t >> 6;
#pragma unroll
  for (int kh = 0; kh < 16; ++kh) {
    const int k = kq * 16 + kh;
    const float asv = asums[kh];
    const float2 c2 = *(const float2*)(cent + (size_t)k * D_ + d0);
    acc[kh * 2]     -= asv * c2.x;
    acc[kh * 2 + 1] -= asv * c2.y;
    float v = acc[kh * 2] * acc[kh * 2] + acc[kh * 2 + 1] * acc[kh * 2 + 1];
#pragma unroll
    for (int o = 32; o > 0; o >>= 1) v += __shfl_down(v, o, 64);
    if (lane == 0) part[kh][wv] = v;
  }
  __syncthreads();
  if (t < 16) {
    const float s = part[t][0] + part[t][1] + part[t][2] + part[t][3];
    scale_s[t] = 0.125f / fmaxf(sqrtf(s), 1e-12f);
  }
  __syncthreads();
#pragma unroll
  for (int kh = 0; kh < 16; ++kh) {
    const int k = kq * 16 + kh;
    const float f = scale_s[kh];
    float2 o;
    o.x = acc[kh * 2] * f;
    o.y = acc[kh * 2 + 1] * f;
    *(float2*)(out + ((size_t)b * K_ + k) * D_ + d0) = o;
  }
}

extern "C" void kernel_launch(void* const* d_in, const int* in_sizes, int n_in,
                              void* d_out, int out_size, void* d_ws, size_t ws_size,
                              hipStream_t stream)
{
  const float* x  = (const float*)d_in[0];   // (B,D,H,W) fp32
  const float* w  = (const float*)d_in[1];   // (K,D) fp32
  const float* ct = (const float*)d_in[2];   // (K,D) fp32
  float* out = (float*)d_out;                // (B, K*D) fp32

  const size_t wf_u16  = (size_t)K_ * D_;            // 32,768 per hi/lo array
  const size_t invn_f  = (size_t)B_ * N_;
  const size_t asum_f  = (size_t)B_ * NT2CNT * K_;
  const size_t a_u16   = (size_t)B_ * K_ * N_;       // unpadded a
  const size_t ap_u16  = (size_t)B_ * K_ * AST;      // padded a'
  const size_t vlad_f  = (size_t)B_ * K_ * D_;       // per partial
  const size_t need_old  = (invn_f + asum_f) * 4 + a_u16 * 2;      // ~10.4 MB
  const size_t need_mfma = need_old + wf_u16 * 2 * 2;              // ~10.5 MB
  const size_t need_v2   = wf_u16 * 2 * 2 + ap_u16 * 2
                         + (invn_f + asum_f + vlad_f * 4) * 4;     // ~44.3 MB

  if (ws_size >= need_v2) {
    u16* wfh = (u16*)d_ws;
    u16* wfl = wfh + wf_u16;
    u16* a_bf = wfl + wf_u16;                          // padded, stride AST
    float* invn_ws   = (float*)(a_bf + ap_u16);
    float* asum_part = invn_ws + invn_f;
    float* vlad_ws   = asum_part + asum_f;             // [4][B][K][D]
    hipLaunchKernelGGL(k_wsplit, dim3(64), dim3(64), 0, stream, w, wfh, wfl);
    hipLaunchKernelGGL(k_logits_mfma, dim3(NT2CNT, B_), dim3(256), 0, stream,
                       x, wfh, wfl, a_bf, invn_ws, asum_part, 1);
    hipLaunchKernelGGL(k_vlad_mfma, dim3(1024), dim3(256), 0, stream,
                       x, a_bf, vlad_ws);
    hipLaunchKernelGGL(k_norm, dim3(512), dim3(256), 0, stream,
                       vlad_ws, asum_part, ct, out);
  } else if (ws_size >= need_mfma) {
    u16* wfh = (u16*)d_ws;
    u16* wfl = wfh + wf_u16;
    float* invn_ws   = (float*)(wfl + wf_u16);
    float* asum_part = invn_ws + invn_f;
    u16* a_bf = (u16*)(asum_part + asum_f);
    hipLaunchKernelGGL(k_wsplit, dim3(64), dim3(64), 0, stream, w, wfh, wfl);
    hipLaunchKernelGGL(k_logits_mfma, dim3(NT2CNT, B_), dim3(256), 0, stream,
                       x, wfh, wfl, a_bf, invn_ws, asum_part, 0);
    hipLaunchKernelGGL(k_vlad, dim3(512), dim3(256), 0, stream,
                       x, a_bf, invn_ws, asum_part, ct, out);
  } else if (ws_size >= need_old) {
    float* invn_ws   = (float*)d_ws;
    float* asum_part = invn_ws + invn_f;
    u16* a_bf = (u16*)(asum_part + asum_f);
    hipLaunchKernelGGL(k_logits, dim3(NT2CNT, B_), dim3(256), 0, stream,
                       x, w, a_bf, invn_ws, asum_part);
    hipLaunchKernelGGL(k_vlad, dim3(512), dim3(256), 0, stream,
                       x, a_bf, invn_ws, asum_part, ct, out);
  } else {
    hipLaunchKernelGGL(k_fused, dim3(256), dim3(256), 0, stream, x, w, ct, out);
  }
}